// Round 7
// baseline (477.520 us; speedup 1.0000x reference)
//
#include <hip/hip_runtime.h>
#include <math.h>

#define BSZ 256
#define DIM 128
#define NHD 4
#define NPATCH 196
#define NACT 15

typedef float f32x4 __attribute__((ext_vector_type(4)));
typedef __bf16 bf16x8 __attribute__((ext_vector_type(8)));
typedef short short8 __attribute__((ext_vector_type(8)));

__device__ __forceinline__ float wred_sum(float v) {
#pragma unroll
    for (int m = 1; m < 64; m <<= 1) v += __shfl_xor(v, m, 64);
    return v;
}
__device__ __forceinline__ float wred_max(float v) {
#pragma unroll
    for (int m = 1; m < 64; m <<= 1) v = fmaxf(v, __shfl_xor(v, m, 64));
    return v;
}
__device__ __forceinline__ ushort f2bf(float f) {  // RNE bf16
    unsigned u = __float_as_uint(f);
    return (ushort)((u + 0x7fffu + ((u >> 16) & 1u)) >> 16);
}

// ---------------------------------------------------------------------------
// Weight convert+transpose to bf16 [N][K] (patch K-permuted), packed.
// ---------------------------------------------------------------------------
__global__ __launch_bounds__(256) void k_wconv(
    const float* __restrict__ pW, const float* __restrict__ qkvW,
    const float* __restrict__ outW, const float* __restrict__ ff1W,
    const float* __restrict__ ff2W, const float* __restrict__ ckvW,
    ushort* __restrict__ o)
{
    int i = blockIdx.x * 256 + threadIdx.x;
    if (i < 98304) {
        int n = i / 768, kp = i % 768;
        int c = kp >> 8, q = kp & 255;
        o[i] = f2bf(pW[(q * 3 + c) * 128 + n]); return;
    }
    i -= 98304;
    if (i < 49152) { int n = i >> 7, k = i & 127; o[98304 + i] = f2bf(qkvW[k * 384 + n]); return; }
    i -= 49152;
    if (i < 16384) { int n = i >> 7, k = i & 127; o[147456 + i] = f2bf(outW[k * 128 + n]); return; }
    i -= 16384;
    if (i < 8192)  { int n = i >> 7, k = i & 127; o[163840 + i] = f2bf(ff1W[k * 64 + n]); return; }
    i -= 8192;
    if (i < 8192)  { int n = i >> 6, k = i & 63;  o[172032 + i] = f2bf(ff2W[k * 128 + n]); return; }
    i -= 8192;
    if (i < 32768) { int n = i >> 7, k = i & 127; o[180224 + i] = f2bf(ckvW[k * 384 + 128 + n]); return; }
}

// ---------------------------------------------------------------------------
// Fused patchify + patch-embed MFMA GEMM (verified r6).
// ---------------------------------------------------------------------------
__global__ __launch_bounds__(256) void k_pgemm(
    const float* __restrict__ img, const ushort* __restrict__ Wt,
    const float* __restrict__ bias, const float* __restrict__ pe,
    float* __restrict__ C, ushort* __restrict__ Cb)
{
    __shared__ ushort As[64 * 64];
    __shared__ ushort Ws[128 * 64];
    const int t = threadIdx.x;
    const int w = t >> 6, l = t & 63;
    const int pb = blockIdx.x;
    const int p = pb >> 2, bq = pb & 3;
    const int hp = p / 14, wp = p % 14;
    const int r0 = p * 256 + bq * 64;
    const int wm = w >> 1, wn = w & 1;
    const int lrow = l & 15, lk = l >> 4;
    const int arow = t >> 2;
    const int b_img = bq * 64 + arow;
    const float* gimg = img + (size_t)b_img * 150528 + hp * (16 * 224) + wp * 16;

    f32x4 acc[2][4];
#pragma unroll
    for (int m = 0; m < 2; ++m)
#pragma unroll
        for (int n = 0; n < 4; ++n) acc[m][n] = (f32x4)0.f;

    for (int kc = 0; kc < 768; kc += 64) {
        const int c = kc >> 8, p1q = (kc >> 6) & 3;
        const float* gc = gimg + c * 50176 + p1q * 4 * 224;
        __syncthreads();
#pragma unroll
        for (int i = 0; i < 4; ++i) {
            const int kq = (t & 3) + 4 * i;
            const int p1 = kq >> 2, p2q = kq & 3;
            const float4 v = *(const float4*)(gc + p1 * 224 + p2q * 4);
            ushort4 o4;
            o4.x = f2bf(v.x); o4.y = f2bf(v.y); o4.z = f2bf(v.z); o4.w = f2bf(v.w);
            const int bo = (kq * 8) ^ ((arow & 7) << 4);
            *(ushort4*)((char*)As + arow * 128 + bo) = o4;
        }
        for (int i2 = t; i2 < 128 * 8; i2 += 256) {
            const int row = i2 >> 3, ch = i2 & 7;
            const int sw = (ch * 16) ^ ((row & 7) << 4);
            *(short8*)((char*)Ws + row * 128 + sw) =
                *(const short8*)(Wt + (size_t)row * 768 + kc + ch * 8);
        }
        __syncthreads();
#pragma unroll
        for (int ks = 0; ks < 2; ++ks) {
            bf16x8 af[2], bfr[4];
#pragma unroll
            for (int m = 0; m < 2; ++m) {
                const int row = wm * 32 + m * 16 + lrow;
                const int col = (ks * 64 + lk * 16) ^ ((row & 7) << 4);
                af[m] = *(const bf16x8*)((const char*)As + row * 128 + col);
            }
#pragma unroll
            for (int n = 0; n < 4; ++n) {
                const int row = wn * 64 + n * 16 + lrow;
                const int col = (ks * 64 + lk * 16) ^ ((row & 7) << 4);
                bfr[n] = *(const bf16x8*)((const char*)Ws + row * 128 + col);
            }
#pragma unroll
            for (int m = 0; m < 2; ++m)
#pragma unroll
                for (int n = 0; n < 4; ++n)
                    acc[m][n] = __builtin_amdgcn_mfma_f32_16x16x32_bf16(
                        af[m], bfr[n], acc[m][n], 0, 0, 0);
        }
    }

    const int crow0 = (l >> 4) * 4;
    const int ccol = l & 15;
#pragma unroll
    for (int m = 0; m < 2; ++m) {
        const int growb = r0 + wm * 32 + m * 16 + crow0;
#pragma unroll
        for (int n = 0; n < 4; ++n) {
            const int gcol = wn * 64 + n * 16 + ccol;
            const float bv = bias[gcol] + pe[p * 128 + gcol];
#pragma unroll
            for (int j = 0; j < 4; ++j) {
                const int grow = growb + j;
                const float v = acc[m][n][j] + bv;
                C[(size_t)grow * 128 + gcol] = v;
                Cb[(size_t)grow * 128 + gcol] = f2bf(v);
            }
        }
    }
}

// ---------------------------------------------------------------------------
// bf16 MFMA GEMM, BM x BN tile (verified).
// ---------------------------------------------------------------------------
template <int BM, int BN>
__global__ __launch_bounds__(256) void k_gemm_bf16(
    const ushort* __restrict__ A, int lda,
    const ushort* __restrict__ Wt, int K,
    const float* __restrict__ bias,
    float* __restrict__ C, ushort* __restrict__ Cb, int ldc,
    const float* __restrict__ pe, int relu)
{
    constexpr int NWN = BN / 64;
    constexpr int NWM = 4 / NWN;
    constexpr int WTM = BM / NWM;
    constexpr int MF = WTM / 16;
    __shared__ ushort As[BM * 64];
    __shared__ ushort Ws[BN * 64];
    const int t = threadIdx.x;
    const int w = t >> 6, l = t & 63;
    const int r0 = blockIdx.x * BM;
    const int n0 = blockIdx.y * BN;
    const int wm = w / NWN, wn = w % NWN;
    const int lrow = l & 15, lk = l >> 4;

    f32x4 acc[MF][4];
#pragma unroll
    for (int m = 0; m < MF; ++m)
#pragma unroll
        for (int n = 0; n < 4; ++n) acc[m][n] = (f32x4)0.f;

    for (int kc = 0; kc < K; kc += 64) {
        __syncthreads();
#pragma unroll
        for (int i = t; i < BM * 8; i += 256) {
            const int row = i >> 3, ch = i & 7;
            const int sw = (ch * 16) ^ ((row & 7) << 4);
            *(short8*)((char*)As + row * 128 + sw) =
                *(const short8*)(A + (size_t)(r0 + row) * lda + kc + ch * 8);
        }
#pragma unroll
        for (int i = t; i < BN * 8; i += 256) {
            const int row = i >> 3, ch = i & 7;
            const int sw = (ch * 16) ^ ((row & 7) << 4);
            *(short8*)((char*)Ws + row * 128 + sw) =
                *(const short8*)(Wt + (size_t)(n0 + row) * K + kc + ch * 8);
        }
        __syncthreads();
#pragma unroll
        for (int ks = 0; ks < 2; ++ks) {
            bf16x8 af[MF], bfr[4];
#pragma unroll
            for (int m = 0; m < MF; ++m) {
                const int row = wm * WTM + m * 16 + lrow;
                const int col = (ks * 64 + lk * 16) ^ ((row & 7) << 4);
                af[m] = *(const bf16x8*)((const char*)As + row * 128 + col);
            }
#pragma unroll
            for (int n = 0; n < 4; ++n) {
                const int row = wn * 64 + n * 16 + lrow;
                const int col = (ks * 64 + lk * 16) ^ ((row & 7) << 4);
                bfr[n] = *(const bf16x8*)((const char*)Ws + row * 128 + col);
            }
#pragma unroll
            for (int m = 0; m < MF; ++m)
#pragma unroll
                for (int n = 0; n < 4; ++n)
                    acc[m][n] = __builtin_amdgcn_mfma_f32_16x16x32_bf16(
                        af[m], bfr[n], acc[m][n], 0, 0, 0);
        }
    }

    const int crow0 = (l >> 4) * 4;
    const int ccol = l & 15;
#pragma unroll
    for (int m = 0; m < MF; ++m) {
        const int growb = r0 + wm * WTM + m * 16 + crow0;
#pragma unroll
        for (int n = 0; n < 4; ++n) {
            const int gcol = n0 + wn * 64 + n * 16 + ccol;
            const float bv = bias[gcol];
#pragma unroll
            for (int j = 0; j < 4; ++j) {
                const int grow = growb + j;
                float v = acc[m][n][j] + bv;
                if (pe) v += pe[(grow >> 8) * 128 + gcol];
                if (relu) v = fmaxf(v, 0.f);
                if (C)  C[(size_t)grow * ldc + gcol] = v;
                if (Cb) Cb[(size_t)grow * ldc + gcol] = f2bf(v);
            }
        }
    }
}

// ---------------------------------------------------------------------------
// bf16 MFMA GEMM 64x128 + residual + LayerNorm fused epilogue (verified r5).
// ---------------------------------------------------------------------------
__global__ __launch_bounds__(256) void k_gemm_ln(
    const ushort* __restrict__ A, int lda,
    const ushort* __restrict__ Wt, int K,
    const float* __restrict__ bias,
    const float* __restrict__ resid,
    const float* __restrict__ lns, const float* __restrict__ lnbi,
    float* __restrict__ Co, ushort* __restrict__ Cb)
{
    __shared__ ushort As[64 * 64];
    __shared__ ushort Ws[128 * 64];
    __shared__ float psum[64][2][2];
    const int t = threadIdx.x;
    const int w = t >> 6, l = t & 63;
    const int r0 = blockIdx.x * 64;
    const int wm = w >> 1, wn = w & 1;
    const int lrow = l & 15, lk = l >> 4;

    f32x4 acc[2][4];
#pragma unroll
    for (int m = 0; m < 2; ++m)
#pragma unroll
        for (int n = 0; n < 4; ++n) acc[m][n] = (f32x4)0.f;

    for (int kc = 0; kc < K; kc += 64) {
        __syncthreads();
#pragma unroll
        for (int i = t; i < 64 * 8; i += 256) {
            const int row = i >> 3, ch = i & 7;
            const int sw = (ch * 16) ^ ((row & 7) << 4);
            *(short8*)((char*)As + row * 128 + sw) =
                *(const short8*)(A + (size_t)(r0 + row) * lda + kc + ch * 8);
        }
#pragma unroll
        for (int i = t; i < 128 * 8; i += 256) {
            const int row = i >> 3, ch = i & 7;
            const int sw = (ch * 16) ^ ((row & 7) << 4);
            *(short8*)((char*)Ws + row * 128 + sw) =
                *(const short8*)(Wt + (size_t)row * K + kc + ch * 8);
        }
        __syncthreads();
#pragma unroll
        for (int ks = 0; ks < 2; ++ks) {
            bf16x8 af[2], bfr[4];
#pragma unroll
            for (int m = 0; m < 2; ++m) {
                const int row = wm * 32 + m * 16 + lrow;
                const int col = (ks * 64 + lk * 16) ^ ((row & 7) << 4);
                af[m] = *(const bf16x8*)((const char*)As + row * 128 + col);
            }
#pragma unroll
            for (int n = 0; n < 4; ++n) {
                const int row = wn * 64 + n * 16 + lrow;
                const int col = (ks * 64 + lk * 16) ^ ((row & 7) << 4);
                bfr[n] = *(const bf16x8*)((const char*)Ws + row * 128 + col);
            }
#pragma unroll
            for (int m = 0; m < 2; ++m)
#pragma unroll
                for (int n = 0; n < 4; ++n)
                    acc[m][n] = __builtin_amdgcn_mfma_f32_16x16x32_bf16(
                        af[m], bfr[n], acc[m][n], 0, 0, 0);
        }
    }

    const int crow0 = (l >> 4) * 4;
    const int ccol = l & 15;
#pragma unroll
    for (int m = 0; m < 2; ++m) {
        const int growb = r0 + wm * 32 + m * 16 + crow0;
#pragma unroll
        for (int n = 0; n < 4; ++n) {
            const int gcol = wn * 64 + n * 16 + ccol;
            const float bv = bias[gcol];
#pragma unroll
            for (int j = 0; j < 4; ++j) {
                float v = acc[m][n][j] + bv;
                if (resid) v += resid[(size_t)(growb + j) * 128 + gcol];
                acc[m][n][j] = v;
            }
        }
    }
#pragma unroll
    for (int m = 0; m < 2; ++m)
#pragma unroll
        for (int j = 0; j < 4; ++j) {
            float s_ = 0.f, q_ = 0.f;
#pragma unroll
            for (int n = 0; n < 4; ++n) {
                const float x = acc[m][n][j];
                s_ += x; q_ += x * x;
            }
#pragma unroll
            for (int mk = 1; mk < 16; mk <<= 1) {
                s_ += __shfl_xor(s_, mk, 64);
                q_ += __shfl_xor(q_, mk, 64);
            }
            if (ccol == 0) {
                const int r = wm * 32 + m * 16 + crow0 + j;
                psum[r][wn][0] = s_;
                psum[r][wn][1] = q_;
            }
        }
    __syncthreads();
    float mean_[2][4], rstd_[2][4];
#pragma unroll
    for (int m = 0; m < 2; ++m)
#pragma unroll
        for (int j = 0; j < 4; ++j) {
            const int r = wm * 32 + m * 16 + crow0 + j;
            const float sum = psum[r][0][0] + psum[r][1][0];
            const float sq  = psum[r][0][1] + psum[r][1][1];
            const float mean = sum * 0.0078125f;
            const float var = sq * 0.0078125f - mean * mean;
            mean_[m][j] = mean;
            rstd_[m][j] = rsqrtf(var + 1e-5f);
        }
#pragma unroll
    for (int m = 0; m < 2; ++m) {
        const int growb = r0 + wm * 32 + m * 16 + crow0;
#pragma unroll
        for (int n = 0; n < 4; ++n) {
            const int gcol = wn * 64 + n * 16 + ccol;
            const float sv = lns[gcol], bv2 = lnbi[gcol];
#pragma unroll
            for (int j = 0; j < 4; ++j) {
                const float y = (acc[m][n][j] - mean_[m][j]) * rstd_[m][j] * sv + bv2;
                const size_t oi = (size_t)(growb + j) * 128 + gcol;
                if (Co) Co[oi] = y;
                if (Cb) Cb[oi] = f2bf(y);
            }
        }
    }
}

// ---------------------------------------------------------------------------
// MFMA flash attention, encoder self-attn (verified r3).
// ---------------------------------------------------------------------------
__global__ __launch_bounds__(256) void k_attn_mfma(
    const ushort* __restrict__ qkv, ushort* __restrict__ ob, float scale)
{
    __shared__ ushort Ks[208 * 40];
    __shared__ ushort Vt[32 * 232];
    __shared__ ushort Ps[4][16 * 232];
    const int bh = blockIdx.x;
    const int b = bh >> 2, h = bh & 3;
    const int t = threadIdx.x, w = t >> 6, l = t & 63;
    const int lr = l & 15, lg = l >> 4;

    for (int idx = t; idx < 784; idx += 256) {
        const int j = idx >> 2, ch = idx & 3;
        const size_t base = ((size_t)j * 256 + b) * 384 + h * 32 + ch * 8;
        *(short8*)(Ks + j * 40 + ch * 8) = *(const short8*)(qkv + base + 128);
        short8 v = *(const short8*)(qkv + base + 256);
#pragma unroll
        for (int q = 0; q < 8; ++q)
            Vt[(ch * 8 + q) * 232 + j] = (ushort)v[q];
    }
    for (int idx = t; idx < 32 * 36; idx += 256)
        Vt[(idx / 36) * 232 + 196 + (idx % 36)] = 0;
    for (int i = l; i < 256; i += 64)
        Ps[w][(i >> 4) * 232 + 208 + (i & 15)] = 0;
    __syncthreads();

    for (int qt = w; qt < 13; qt += 4) {
        int qr = qt * 16 + lr; if (qr > 195) qr = 195;
        const bf16x8 qf = *(const bf16x8*)(qkv + ((size_t)qr * 256 + b) * 384 + h * 32 + lg * 8);

        f32x4 s[13];
#pragma unroll
        for (int jn = 0; jn < 13; ++jn) {
            const bf16x8 kf = *(const bf16x8*)(Ks + (jn * 16 + lr) * 40 + lg * 8);
            s[jn] = __builtin_amdgcn_mfma_f32_16x16x32_bf16(qf, kf, (f32x4)0.f, 0, 0, 0);
        }
        if (lr >= 4) {
            s[12][0] = -3.0e38f; s[12][1] = -3.0e38f;
            s[12][2] = -3.0e38f; s[12][3] = -3.0e38f;
        }

        float inv[4];
        ushort* pw = Ps[w];
#pragma unroll
        for (int j = 0; j < 4; ++j) {
            float m = s[0][j];
#pragma unroll
            for (int jn = 1; jn < 13; ++jn) m = fmaxf(m, s[jn][j]);
            m = fmaxf(m, __shfl_xor(m, 1, 64));
            m = fmaxf(m, __shfl_xor(m, 2, 64));
            m = fmaxf(m, __shfl_xor(m, 4, 64));
            m = fmaxf(m, __shfl_xor(m, 8, 64));
            float sum = 0.f;
#pragma unroll
            for (int jn = 0; jn < 13; ++jn) {
                const float p = __expf((s[jn][j] - m) * scale);
                s[jn][j] = p;
                sum += p;
            }
            sum += __shfl_xor(sum, 1, 64);
            sum += __shfl_xor(sum, 2, 64);
            sum += __shfl_xor(sum, 4, 64);
            sum += __shfl_xor(sum, 8, 64);
            inv[j] = 1.0f / sum;
        }
#pragma unroll
        for (int jn = 0; jn < 13; ++jn)
#pragma unroll
            for (int j = 0; j < 4; ++j)
                pw[(lg * 4 + j) * 232 + jn * 16 + lr] = f2bf(s[jn][j]);

        f32x4 o0 = (f32x4)0.f, o1 = (f32x4)0.f;
#pragma unroll
        for (int kt = 0; kt < 7; ++kt) {
            const bf16x8 pf = *(const bf16x8*)(pw + lr * 232 + kt * 32 + lg * 8);
            const bf16x8 v0 = *(const bf16x8*)(Vt + lr * 232 + kt * 32 + lg * 8);
            const bf16x8 v1 = *(const bf16x8*)(Vt + (16 + lr) * 232 + kt * 32 + lg * 8);
            o0 = __builtin_amdgcn_mfma_f32_16x16x32_bf16(pf, v0, o0, 0, 0, 0);
            o1 = __builtin_amdgcn_mfma_f32_16x16x32_bf16(pf, v1, o1, 0, 0, 0);
        }
#pragma unroll
        for (int j = 0; j < 4; ++j) {
            const int r = qt * 16 + lg * 4 + j;
            if (r < 196) {
                const size_t o = ((size_t)r * 256 + b) * 128 + h * 32;
                ob[o + lr]      = f2bf(o0[j] * inv[j]);
                ob[o + 16 + lr] = f2bf(o1[j] * inv[j]);
            }
        }
    }
}

// ---------------------------------------------------------------------------
// Fused attention (f32, decoder paths; verified r1).
// ---------------------------------------------------------------------------
__global__ __launch_bounds__(256) void k_attn(
    const float* __restrict__ qp, int qstride,
    const float* __restrict__ kvp, int kvstride, int koff, int voff,
    float* __restrict__ op, ushort* __restrict__ ob,
    int Lq, int Lk, float scale)
{
    __shared__ float Kl[196 * 36];
    __shared__ float Vl[196 * 32];
    __shared__ float pbuf[4][256];
    const int bh = blockIdx.x;
    const int b = bh >> 2;
    const int h = bh & 3;
    const int t = threadIdx.x;
    const int w = t >> 6;
    const int l = t & 63;

    for (int idx = t; idx < Lk * 8; idx += 256) {
        const int j = idx >> 3;
        const int kq = idx & 7;
        const size_t row = ((size_t)j * 256 + b) * kvstride + h * 32 + kq * 4;
        *(float4*)(&Kl[j * 36 + kq * 4]) = *(const float4*)(kvp + row + koff);
        *(float4*)(&Vl[j * 32 + kq * 4]) = *(const float4*)(kvp + row + voff);
    }
    if ((Lk & 1) && t < 8) *(float4*)(&Vl[Lk * 32 + t * 4]) = make_float4(0.f, 0.f, 0.f, 0.f);
    __syncthreads();

    const int Lh = (Lk + 1) >> 1;
    const int half = l >> 5;
    const int kk = l & 31;
    const int jb = half * Lh;

    for (int jq = w; jq < Lq; jq += 4) {
        const float* qrow = qp + ((size_t)jq * 256 + b) * qstride + h * 32;
        float4 q4[8];
#pragma unroll
        for (int kq = 0; kq < 8; ++kq) q4[kq] = *(const float4*)(qrow + kq * 4);

        float s[4];
#pragma unroll
        for (int r = 0; r < 4; ++r) {
            const int j = l + (r << 6);
            float acc = -3.0e38f;
            if (j < Lk) {
                acc = 0.f;
#pragma unroll
                for (int kq = 0; kq < 8; ++kq) {
                    const float4 kv = *(const float4*)(&Kl[j * 36 + kq * 4]);
                    acc += q4[kq].x * kv.x + q4[kq].y * kv.y +
                           q4[kq].z * kv.z + q4[kq].w * kv.w;
                }
                acc *= scale;
            }
            s[r] = acc;
        }
        float m = fmaxf(fmaxf(s[0], s[1]), fmaxf(s[2], s[3]));
        m = wred_max(m);
        float sum = 0.f;
#pragma unroll
        for (int r = 0; r < 4; ++r) {
            const int j = l + (r << 6);
            float p = __expf(s[r] - m);
            if (j >= Lk) p = 0.f;
            pbuf[w][j] = p;
            sum += p;
        }
        sum = wred_sum(sum);
        const float inv = 1.0f / sum;
        __threadfence_block();

        float o = 0.f;
        for (int jj = 0; jj < Lh; ++jj) {
            const float pv = pbuf[w][jb + jj];
            const float vv = Vl[(jb + jj) * 32 + kk];
            o += pv * vv;
        }
        o += __shfl_xor(o, 32, 64);
        o *= inv;
        if (l < 32) {
            const size_t oi = ((size_t)jq * 256 + b) * 128 + h * 32 + l;
            if (op) op[oi] = o;
            if (ob) ob[oi] = f2bf(o);
        }
        __threadfence_block();
    }
}

// ---------------------------------------------------------------------------
// Decoder f32 GEMM, 64x128 tile, fused epilogue modes (verified r5).
// ---------------------------------------------------------------------------
__global__ __launch_bounds__(256) void k_gdec(
    const float* __restrict__ A, int K,
    const float* __restrict__ W, int wstride,
    const float* __restrict__ bias,
    const float* __restrict__ resid,
    const float* __restrict__ ln1s, const float* __restrict__ ln1b,
    const float* __restrict__ ln2s, const float* __restrict__ ln2b,
    const float* __restrict__ w2, const float* __restrict__ b2h,
    float* __restrict__ C, int ldc, float* __restrict__ qout)
{
    __shared__ float As[64 * 68];
    __shared__ float Ws2[64 * 132];
    const int t = threadIdx.x;
    const int r0 = blockIdx.x * 64;
    const int n0 = blockIdx.y * 128;
    const int tx = t & 31, ty = t >> 5;

    float4 acc[8];
#pragma unroll
    for (int i = 0; i < 8; ++i) acc[i] = make_float4(0.f, 0.f, 0.f, 0.f);

    for (int kc = 0; kc < K; kc += 64) {
        __syncthreads();
        for (int idx = t; idx < 1024; idx += 256) {
            const int row = idx >> 4, kk = idx & 15;
            *(float4*)&As[row * 68 + kk * 4] =
                *(const float4*)(A + (size_t)(r0 + row) * K + kc + kk * 4);
        }
        for (int idx = t; idx < 2048; idx += 256) {
            const int kk = idx >> 5, nq = idx & 31;
            *(float4*)&Ws2[kk * 132 + nq * 4] =
                *(const float4*)(W + (size_t)(kc + kk) * wstride + n0 + nq * 4);
        }
        __syncthreads();
        for (int k = 0; k < 64; ++k) {
            const float4 wv = *(const float4*)&Ws2[k * 132 + tx * 4];
#pragma unroll
            for (int i = 0; i < 8; ++i) {
                const float av = As[(ty * 8 + i) * 68 + k];
                acc[i].x += av * wv.x; acc[i].y += av * wv.y;
                acc[i].z += av * wv.z; acc[i].w += av * wv.w;
            }
        }
    }

    const float4 bv = *(const float4*)(bias + n0 + tx * 4);
#pragma unroll
    for (int i = 0; i < 8; ++i) {
        acc[i].x += bv.x; acc[i].y += bv.y; acc[i].z += bv.z; acc[i].w += bv.w;
        if (resid) {
            const float4 rr = *(const float4*)(resid + (size_t)(r0 + ty * 8 + i) * 128 + tx * 4);
            acc[i].x += rr.x; acc[i].y += rr.y; acc[i].z += rr.z; acc[i].w += rr.w;
        }
    }

    if (ln1s) {
        const float4 s1 = *(const float4*)(ln1s + tx * 4);
        const float4 b1 = *(const float4*)(ln1b + tx * 4);
#pragma unroll
        for (int i = 0; i < 8; ++i) {
            float s_ = acc[i].x + acc[i].y + acc[i].z + acc[i].w;
            float q_ = acc[i].x * acc[i].x + acc[i].y * acc[i].y +
                       acc[i].z * acc[i].z + acc[i].w * acc[i].w;
#pragma unroll
            for (int mk = 1; mk < 32; mk <<= 1) {
                s_ += __shfl_xor(s_, mk, 64);
                q_ += __shfl_xor(q_, mk, 64);
            }
            const float mean = s_ * 0.0078125f;
            const float rstd = rsqrtf(q_ * 0.0078125f - mean * mean + 1e-5f);
            acc[i].x = (acc[i].x - mean) * rstd * s1.x + b1.x;
            acc[i].y = (acc[i].y - mean) * rstd * s1.y + b1.y;
            acc[i].z = (acc[i].z - mean) * rstd * s1.z + b1.z;
            acc[i].w = (acc[i].w - mean) * rstd * s1.w + b1.w;
        }
        if (ln2s) {
            const float4 s2 = *(const float4*)(ln2s + tx * 4);
            const float4 b2 = *(const float4*)(ln2b + tx * 4);
#pragma unroll
            for (int i = 0; i < 8; ++i) {
                float s_ = acc[i].x + acc[i].y + acc[i].z + acc[i].w;
                float q_ = acc[i].x * acc[i].x + acc[i].y * acc[i].y +
                           acc[i].z * acc[i].z + acc[i].w * acc[i].w;
#pragma unroll
                for (int mk = 1; mk < 32; mk <<= 1) {
                    s_ += __shfl_xor(s_, mk, 64);
                    q_ += __shfl_xor(q_, mk, 64);
                }
                const float mean = s_ * 0.0078125f;
                const float rstd = rsqrtf(q_ * 0.0078125f - mean * mean + 1e-5f);
                acc[i].x = (acc[i].x - mean) * rstd * s2.x + b2.x;
                acc[i].y = (acc[i].y - mean) * rstd * s2.y + b2.y;
                acc[i].z = (acc[i].z - mean) * rstd * s2.z + b2.z;
                acc[i].w = (acc[i].w - mean) * rstd * s2.w + b2.w;
            }
        }
    }

    if (w2) {  // head: relu then dot with w2 -> qout[b*15 + i_act]
        const float4 w4 = *(const float4*)(w2 + tx * 4);
        const float bh = b2h[0];
#pragma unroll
        for (int i = 0; i < 8; ++i) {
            const float hx = fmaxf(acc[i].x, 0.f), hy = fmaxf(acc[i].y, 0.f);
            const float hz = fmaxf(acc[i].z, 0.f), hw = fmaxf(acc[i].w, 0.f);
            float d = hx * w4.x + hy * w4.y + hz * w4.z + hw * w4.w;
#pragma unroll
            for (int mk = 1; mk < 32; mk <<= 1) d += __shfl_xor(d, mk, 64);
            if (tx == 0) {
                const int token = r0 + ty * 8 + i;
                qout[(token & 255) * 15 + (token >> 8)] = d + bh;
            }
        }
        return;
    }
#pragma unroll
    for (int i = 0; i < 8; ++i)
        *(float4*)(C + (size_t)(r0 + ty * 8 + i) * ldc + n0 + tx * 4) = acc[i];
}

// ---------------------------------------------------------------------------
// f32 tiled GEMM 64x64 (decoder ff1; verified r1).
// ---------------------------------------------------------------------------
__global__ __launch_bounds__(256) void k_gemm64(
    const float* __restrict__ A, int K,
    const float* __restrict__ W, int wstride,
    const float* __restrict__ bias,
    float* __restrict__ C, int cstride, int relu)
{
    __shared__ float As[64 * 132];
    __shared__ float Ws2[128 * 68];
    const int t = threadIdx.x;
    const int r0 = blockIdx.x * 64;
    const int n0 = blockIdx.y * 64;
    const int as = K + 4;
    const int lg = (K == 128) ? 5 : 4;
    const int kmask = (K >> 2) - 1;

    for (int idx = t; idx < (K << 4); idx += 256) {
        const int row = idx >> lg;
        const int kk = idx & kmask;
        *(float4*)(&As[row * as + kk * 4]) =
            *(const float4*)(A + (size_t)(r0 + row) * K + kk * 4);
    }
    for (int idx = t; idx < (K << 4); idx += 256) {
        const int kk = idx >> 4;
        const int nq = idx & 15;
        *(float4*)(&Ws2[kk * 68 + nq * 4]) =
            *(const float4*)(W + (size_t)kk * wstride + n0 + nq * 4);
    }
    __syncthreads();

    const int tx = t & 15, ty = t >> 4;
    float4 acc[4];
#pragma unroll
    for (int i = 0; i < 4; ++i) acc[i] = make_float4(0.f, 0.f, 0.f, 0.f);
    const float* arow = &As[(ty * 4) * as];
    for (int k = 0; k < K; ++k) {
        const float4 wv = *(const float4*)(&Ws2[k * 68 + tx * 4]);
#pragma unroll
        for (int i = 0; i < 4; ++i) {
            const float av = arow[i * as + k];
            acc[i].x += av * wv.x; acc[i].y += av * wv.y;
            acc[i].z += av * wv.z; acc[i].w += av * wv.w;
        }
    }
    const float4 bv = *(const float4*)(bias + n0 + tx * 4);
#pragma unroll
    for (int i = 0; i < 4; ++i) {
        float4 o;
        o.x = acc[i].x + bv.x; o.y = acc[i].y + bv.y;
        o.z = acc[i].z + bv.z; o.w = acc[i].w + bv.w;
        if (relu) {
            o.x = fmaxf(o.x, 0.f); o.y = fmaxf(o.y, 0.f);
            o.z = fmaxf(o.z, 0.f); o.w = fmaxf(o.w, 0.f);
        }
        *(float4*)(C + (size_t)(r0 + ty * 4 + i) * cstride + n0 + tx * 4) = o;
    }
}

// ---------------------------------------------------------------------------
// Parallel small f32 GEMM for the sketch MLP: C[M,N] = act(A[M,K] @ W[K,N] + b)
// 64x64 tile, 4x4 regs/thread, LDS-staged, K-remainder and N-edge guarded.
// grid (M/64, ceil(N/64)).
// ---------------------------------------------------------------------------
__global__ __launch_bounds__(256) void k_sgemm(
    const float* __restrict__ A, int K,
    const float* __restrict__ W, int N,
    const float* __restrict__ bias,
    float* __restrict__ C, int ldc, int relu)
{
    __shared__ float As[64 * 68];
    __shared__ float Ws[64 * 68];
    const int t = threadIdx.x;
    const int r0 = blockIdx.x * 64;
    const int n0 = blockIdx.y * 64;
    const int tx = t & 15, ty = t >> 4;

    f32x4 acc[4];
#pragma unroll
    for (int i = 0; i < 4; ++i) acc[i] = (f32x4)0.f;

    for (int kc = 0; kc < K; kc += 64) {
        __syncthreads();
        for (int idx = t; idx < 1024; idx += 256) {
            const int row = idx >> 4, kq = idx & 15;
            f32x4 v = (f32x4)0.f;
            const int kb = kc + kq * 4;
            if (kb + 3 < K) {
                const float4 g = *(const float4*)(A + (size_t)(r0 + row) * K + kb);
                v[0] = g.x; v[1] = g.y; v[2] = g.z; v[3] = g.w;
            } else {
#pragma unroll
                for (int j = 0; j < 4; ++j)
                    if (kb + j < K) v[j] = A[(size_t)(r0 + row) * K + kb + j];
            }
            *(f32x4*)&As[row * 68 + kq * 4] = v;
        }
        for (int idx = t; idx < 1024; idx += 256) {
            const int kk = idx >> 4, nq = idx & 15;
            const int gk = kc + kk, col = n0 + nq * 4;
            f32x4 v = (f32x4)0.f;
            if (gk < K) {
                if (col + 4 <= N) {
                    const float4 g = *(const float4*)(W + (size_t)gk * N + col);
                    v[0] = g.x; v[1] = g.y; v[2] = g.z; v[3] = g.w;
                } else {
#pragma unroll
                    for (int j = 0; j < 4; ++j)
                        if (col + j < N) v[j] = W[(size_t)gk * N + col + j];
                }
            }
            *(f32x4*)&Ws[kk * 68 + nq * 4] = v;
        }
        __syncthreads();
        for (int k = 0; k < 64; ++k) {
            const f32x4 wv = *(const f32x4*)&Ws[k * 68 + tx * 4];
#pragma unroll
            for (int i = 0; i < 4; ++i) {
                const float av = As[(ty * 4 + i) * 68 + k];
                acc[i] += av * wv;
            }
        }
    }

#pragma unroll
    for (int i = 0; i < 4; ++i) {
#pragma unroll
        for (int j = 0; j < 4; ++j) {
            const int col = n0 + tx * 4 + j;
            if (col < N) {
                float v = acc[i][j] + bias[col];
                if (relu) v = fmaxf(v, 0.f);
                C[(size_t)(r0 + ty * 4 + i) * ldc + col] = v;
            }
        }
    }
}

// ---------------------------------------------------------------------------
// Action-token embedding (verified r4 + LDS-staged s3).
// ---------------------------------------------------------------------------
__global__ __launch_bounds__(128) void k_tgt(
    const float* __restrict__ s3, const float* __restrict__ ang,
    const float* __restrict__ px, const float* __restrict__ py,
    const float* __restrict__ W, const float* __restrict__ bi,
    float* __restrict__ tg)
{
    __shared__ float s3l[100];
    const int b = blockIdx.x;
    const int d = threadIdx.x;
    if (d < 100) s3l[d] = s3[(size_t)b * 100 + d];
    __syncthreads();
    float acc = bi[d] + ang[b] * W[15 * 128 + d] + px[b] * W[16 * 128 + d] +
                py[b] * W[17 * 128 + d];
    for (int k = 0; k < 100; ++k) acc += s3l[k] * W[(18 + k) * 128 + d];
#pragma unroll
    for (int i = 0; i < 15; ++i)
        tg[((size_t)i * 256 + b) * 128 + d] = acc + W[i * 128 + d];
}

// ---------------------------------------------------------------------------
extern "C" void kernel_launch(void* const* d_in, const int* in_sizes, int n_in,
                              void* d_out, int out_size, void* d_ws, size_t ws_size,
                              hipStream_t stream)
{
    (void)in_sizes; (void)n_in; (void)out_size; (void)ws_size;
    const float* image      = (const float*)d_in[0];
    const float* angle      = (const float*)d_in[1];
    const float* pos_x      = (const float*)d_in[2];
    const float* pos_y      = (const float*)d_in[3];
    const float* sk         = (const float*)d_in[4];
    const float* patch_W    = (const float*)d_in[5];
    const float* patch_b    = (const float*)d_in[6];
    const float* pos_emb    = (const float*)d_in[7];
    const float* enc_qkv_W  = (const float*)d_in[8];
    const float* enc_qkv_b  = (const float*)d_in[9];
    const float* enc_out_W  = (const float*)d_in[10];
    const float* enc_out_b  = (const float*)d_in[11];
    const float* enc_ln1_s  = (const float*)d_in[12];
    const float* enc_ln1_b  = (const float*)d_in[13];
    const float* enc_ff1_W  = (const float*)d_in[14];
    const float* enc_ff1_b  = (const float*)d_in[15];
    const float* enc_ff2_W  = (const float*)d_in[16];
    const float* enc_ff2_b  = (const float*)d_in[17];
    const float* enc_ln2_s  = (const float*)d_in[18];
    const float* enc_ln2_b  = (const float*)d_in[19];
    const float* dec_sa_qkv_W = (const float*)d_in[20];
    const float* dec_sa_qkv_b = (const float*)d_in[21];
    const float* dec_sa_out_W = (const float*)d_in[22];
    const float* dec_sa_out_b = (const float*)d_in[23];
    const float* dec_ca_qkv_W = (const float*)d_in[24];
    const float* dec_ca_qkv_b = (const float*)d_in[25];
    const float* dec_ca_out_W = (const float*)d_in[26];
    const float* dec_ca_out_b = (const float*)d_in[27];
    const float* dec_ln1_s  = (const float*)d_in[28];
    const float* dec_ln1_b  = (const float*)d_in[29];
    const float* dec_ln2_s  = (const float*)d_in[30];
    const float* dec_ln2_b  = (const float*)d_in[31];
    const float* dec_ln3_s  = (const float*)d_in[32];
    const float* dec_ln3_b  = (const float*)d_in[33];
    const float* dec_ff1_W  = (const float*)d_in[34];
    const float* dec_ff1_b  = (const float*)d_in[35];
    const float* dec_ff2_W  = (const float*)d_in[36];
    const float* dec_ff2_b  = (const float*)d_in[37];
    const float* dec_norm_s = (const float*)d_in[38];
    const float* dec_norm_b = (const float*)d_in[39];
    const float* sk1_W = (const float*)d_in[40];
    const float* sk1_b = (const float*)d_in[41];
    const float* sk2_W = (const float*)d_in[42];
    const float* sk2_b = (const float*)d_in[43];
    const float* sk3_W = (const float*)d_in[44];
    const float* sk3_b = (const float*)d_in[45];
    const float* act_W = (const float*)d_in[46];
    const float* act_b = (const float*)d_in[47];
    const float* l1_W  = (const float*)d_in[48];
    const float* l1_b  = (const float*)d_in[49];
    const float* l2_W  = (const float*)d_in[50];
    const float* l2_b  = (const float*)d_in[51];

    // Workspace (float offsets)
    float* ws = (float*)d_ws;
    float* S0   = ws;               // src f32 residual stream  [6,422,528]
    float* QKVr = ws + 6422528;     // big overlay region       [19,267,584]
    float* T0   = ws + 25690112;    // decoder attn out f32     [6,422,528]
    float* T1   = ws + 32112640;    // M0b bf16 home            [6,422,528]
    float* F1   = ws + 38535168;    // F1b bf16 / dec DF1       [3,211,264]
    float* M0r  = ws + 41746432;    // srcb/T0b | lnb bf16      [6,422,528]
    float* S1s  = ws + 48168960;    // sketch h1 [65536]
    float* S2s  = S1s + 65536;      // sketch h2 [65536]
    float* S3s  = S2s + 65536;      // sketch out [25600]
    float* TG   = S3s + 25600;      // tgt f32 15*256*128
    ushort* WTS = (ushort*)(ws + 48817152);

    // Overlays
    ushort* QKVb = (ushort*)QKVr;            // enc QKV bf16 [50176][384]
    float*  KV   = QKVr;                     // cross K/V f32 [50176][256]
    float* DQKV = QKVr + 12845056;           // dec self QKV f32
    float* DQ   = QKVr + 14319616;           // dec cross Q f32
    float* DH   = QKVr + 14811136;           // head hidden f32
    float* DT0  = T0;
    float* DF1  = F1;
    ushort* srcb = (ushort*)M0r;
    ushort* T0b  = (ushort*)M0r;             // disjoint lifetime with srcb
    ushort* lnb  = (ushort*)(M0r + 3211264);
    ushort* F1b  = (ushort*)F1;
    ushort* M0b  = (ushort*)T1;
    ushort* wt_patch = WTS;
    ushort* wt_qkv   = WTS + 98304;
    ushort* wt_out   = WTS + 147456;
    ushort* wt_ff1   = WTS + 163840;
    ushort* wt_ff2   = WTS + 172032;
    ushort* wt_ckv   = WTS + 180224;

    const float rs = 0.17677669529663687f;  // 1/sqrt(32)

    // ---- prep: weights + sketch MLP + action tokens ----
    k_wconv<<<dim3(832), 256, 0, stream>>>(patch_W, enc_qkv_W, enc_out_W,
                                           enc_ff1_W, enc_ff2_W, dec_ca_qkv_W, WTS);
    k_sgemm<<<dim3(4, 4), 256, 0, stream>>>(sk, 200, sk1_W, 256, sk1_b, S1s, 256, 1);
    k_sgemm<<<dim3(4, 4), 256, 0, stream>>>(S1s, 256, sk2_W, 256, sk2_b, S2s, 256, 1);
    k_sgemm<<<dim3(4, 2), 256, 0, stream>>>(S2s, 256, sk3_W, 100, sk3_b, S3s, 100, 0);
    k_tgt<<<dim3(256), 128, 0, stream>>>(S3s, angle, pos_x, pos_y, act_W, act_b, TG);

    // ---- encoder ----
    k_pgemm<<<dim3(784), 256, 0, stream>>>(
        image, wt_patch, patch_b, pos_emb, S0, srcb);
    k_gemm_bf16<64, 128><<<dim3(784, 3), 256, 0, stream>>>(
        srcb, 128, wt_qkv, 128, enc_qkv_b, nullptr, QKVb, 384, nullptr, 0);
    k_attn_mfma<<<dim3(1024), 256, 0, stream>>>(QKVb, T0b, rs);
    k_gemm_ln<<<dim3(784), 256, 0, stream>>>(                 // out-proj + LN1
        T0b, 128, wt_out, 128, enc_out_b, S0, enc_ln1_s, enc_ln1_b, S0, lnb);
    k_gemm_bf16<64, 64><<<dim3(784, 1), 256, 0, stream>>>(    // FF1 + relu
        lnb, 128, wt_ff1, 128, enc_ff1_b, nullptr, F1b, 64, nullptr, 1);
    k_gemm_ln<<<dim3(784), 256, 0, stream>>>(                 // FF2 + LN2
        F1b, 64, wt_ff2, 64, enc_ff2_b, S0, enc_ln2_s, enc_ln2_b, nullptr, M0b);
    k_gemm_bf16<64, 128><<<dim3(784, 2), 256, 0, stream>>>(   // cross K/V
        M0b, 128, wt_ckv, 128, dec_ca_qkv_b + 128, KV, nullptr, 256, nullptr, 0);

    // ---- decoder ----
    k_gdec<<<dim3(60, 3), 256, 0, stream>>>(                  // self QKV
        TG, 128, dec_sa_qkv_W, 384, dec_sa_qkv_b, nullptr,
        nullptr, nullptr, nullptr, nullptr, nullptr, nullptr, DQKV, 384, nullptr);
    k_attn<<<dim3(1024), 256, 0, stream>>>(DQKV, 384, DQKV, 384, 128, 256,
                                           DT0, nullptr, 15, 15, rs);
    k_gdec<<<dim3(60, 1), 256, 0, stream>>>(                  // self out + LN1
        DT0, 128, dec_sa_out_W, 128, dec_sa_out_b, TG,
        dec_ln1_s, dec_ln1_b, nullptr, nullptr, nullptr, nullptr, TG, 128, nullptr);
    k_gdec<<<dim3(60, 1), 256, 0, stream>>>(                  // cross Q
        TG, 128, dec_ca_qkv_W, 384, dec_ca_qkv_b, nullptr,
        nullptr, nullptr, nullptr, nullptr, nullptr, nullptr, DQ, 128, nullptr);
    k_attn<<<dim3(1024), 256, 0, stream>>>(DQ, 128, KV, 256, 0, 128,
                                           DT0, nullptr, 15, 196, rs);
    k_gdec<<<dim3(60, 1), 256, 0, stream>>>(                  // cross out + LN2
        DT0, 128, dec_ca_out_W, 128, dec_ca_out_b, TG,
        dec_ln2_s, dec_ln2_b, nullptr, nullptr, nullptr, nullptr, TG, 128, nullptr);
    k_gemm64<<<dim3(60, 1), 256, 0, stream>>>(                // dec FF1 + relu
        TG, 128, dec_ff1_W, 64, dec_ff1_b, DF1, 64, 1);
    k_gdec<<<dim3(60, 1), 256, 0, stream>>>(                  // FF2 + LN3 + norm
        DF1, 64, dec_ff2_W, 128, dec_ff2_b, TG,
        dec_ln3_s, dec_ln3_b, dec_norm_s, dec_norm_b, nullptr, nullptr,
        DT0, 128, nullptr);
    k_gdec<<<dim3(60, 1), 256, 0, stream>>>(                  // l1 + head dot
        DT0, 128, l1_W, 128, l1_b, nullptr,
        nullptr, nullptr, nullptr, nullptr, l2_W, l2_b,
        DH, 128, (float*)d_out);
}

// Round 8
// 403.238 us; speedup vs baseline: 1.1842x; 1.1842x over previous
//
#include <hip/hip_runtime.h>
#include <math.h>

#define BSZ 256
#define DIM 128
#define NHD 4
#define NPATCH 196
#define NACT 15

typedef float f32x4 __attribute__((ext_vector_type(4)));
typedef __bf16 bf16x8 __attribute__((ext_vector_type(8)));
typedef short short8 __attribute__((ext_vector_type(8)));

__device__ __forceinline__ float wred_sum(float v) {
#pragma unroll
    for (int m = 1; m < 64; m <<= 1) v += __shfl_xor(v, m, 64);
    return v;
}
__device__ __forceinline__ float wred_max(float v) {
#pragma unroll
    for (int m = 1; m < 64; m <<= 1) v = fmaxf(v, __shfl_xor(v, m, 64));
    return v;
}
__device__ __forceinline__ ushort f2bf(float f) {  // RNE bf16
    unsigned u = __float_as_uint(f);
    return (ushort)((u + 0x7fffu + ((u >> 16) & 1u)) >> 16);
}

// ---------------------------------------------------------------------------
// Weight convert+transpose to bf16 [N][K] (patch K-permuted), packed.
// ---------------------------------------------------------------------------
__global__ __launch_bounds__(256) void k_wconv(
    const float* __restrict__ pW, const float* __restrict__ qkvW,
    const float* __restrict__ outW, const float* __restrict__ ff1W,
    const float* __restrict__ ff2W, const float* __restrict__ ckvW,
    ushort* __restrict__ o)
{
    int i = blockIdx.x * 256 + threadIdx.x;
    if (i < 98304) {
        int n = i / 768, kp = i % 768;
        int c = kp >> 8, q = kp & 255;
        o[i] = f2bf(pW[(q * 3 + c) * 128 + n]); return;
    }
    i -= 98304;
    if (i < 49152) { int n = i >> 7, k = i & 127; o[98304 + i] = f2bf(qkvW[k * 384 + n]); return; }
    i -= 49152;
    if (i < 16384) { int n = i >> 7, k = i & 127; o[147456 + i] = f2bf(outW[k * 128 + n]); return; }
    i -= 16384;
    if (i < 8192)  { int n = i >> 7, k = i & 127; o[163840 + i] = f2bf(ff1W[k * 64 + n]); return; }
    i -= 8192;
    if (i < 8192)  { int n = i >> 6, k = i & 63;  o[172032 + i] = f2bf(ff2W[k * 128 + n]); return; }
    i -= 8192;
    if (i < 32768) { int n = i >> 7, k = i & 127; o[180224 + i] = f2bf(ckvW[k * 384 + 128 + n]); return; }
}

// ---------------------------------------------------------------------------
// Fused patchify + patch-embed MFMA GEMM (verified r6).
// ---------------------------------------------------------------------------
__global__ __launch_bounds__(256) void k_pgemm(
    const float* __restrict__ img, const ushort* __restrict__ Wt,
    const float* __restrict__ bias, const float* __restrict__ pe,
    float* __restrict__ C, ushort* __restrict__ Cb)
{
    __shared__ ushort As[64 * 64];
    __shared__ ushort Ws[128 * 64];
    const int t = threadIdx.x;
    const int w = t >> 6, l = t & 63;
    const int pb = blockIdx.x;
    const int p = pb >> 2, bq = pb & 3;
    const int hp = p / 14, wp = p % 14;
    const int r0 = p * 256 + bq * 64;
    const int wm = w >> 1, wn = w & 1;
    const int lrow = l & 15, lk = l >> 4;
    const int arow = t >> 2;
    const int b_img = bq * 64 + arow;
    const float* gimg = img + (size_t)b_img * 150528 + hp * (16 * 224) + wp * 16;

    f32x4 acc[2][4];
#pragma unroll
    for (int m = 0; m < 2; ++m)
#pragma unroll
        for (int n = 0; n < 4; ++n) acc[m][n] = (f32x4)0.f;

    for (int kc = 0; kc < 768; kc += 64) {
        const int c = kc >> 8, p1q = (kc >> 6) & 3;
        const float* gc = gimg + c * 50176 + p1q * 4 * 224;
        __syncthreads();
#pragma unroll
        for (int i = 0; i < 4; ++i) {
            const int kq = (t & 3) + 4 * i;
            const int p1 = kq >> 2, p2q = kq & 3;
            const float4 v = *(const float4*)(gc + p1 * 224 + p2q * 4);
            ushort4 o4;
            o4.x = f2bf(v.x); o4.y = f2bf(v.y); o4.z = f2bf(v.z); o4.w = f2bf(v.w);
            const int bo = (kq * 8) ^ ((arow & 7) << 4);
            *(ushort4*)((char*)As + arow * 128 + bo) = o4;
        }
        for (int i2 = t; i2 < 128 * 8; i2 += 256) {
            const int row = i2 >> 3, ch = i2 & 7;
            const int sw = (ch * 16) ^ ((row & 7) << 4);
            *(short8*)((char*)Ws + row * 128 + sw) =
                *(const short8*)(Wt + (size_t)row * 768 + kc + ch * 8);
        }
        __syncthreads();
#pragma unroll
        for (int ks = 0; ks < 2; ++ks) {
            bf16x8 af[2], bfr[4];
#pragma unroll
            for (int m = 0; m < 2; ++m) {
                const int row = wm * 32 + m * 16 + lrow;
                const int col = (ks * 64 + lk * 16) ^ ((row & 7) << 4);
                af[m] = *(const bf16x8*)((const char*)As + row * 128 + col);
            }
#pragma unroll
            for (int n = 0; n < 4; ++n) {
                const int row = wn * 64 + n * 16 + lrow;
                const int col = (ks * 64 + lk * 16) ^ ((row & 7) << 4);
                bfr[n] = *(const bf16x8*)((const char*)Ws + row * 128 + col);
            }
#pragma unroll
            for (int m = 0; m < 2; ++m)
#pragma unroll
                for (int n = 0; n < 4; ++n)
                    acc[m][n] = __builtin_amdgcn_mfma_f32_16x16x32_bf16(
                        af[m], bfr[n], acc[m][n], 0, 0, 0);
        }
    }

    const int crow0 = (l >> 4) * 4;
    const int ccol = l & 15;
#pragma unroll
    for (int m = 0; m < 2; ++m) {
        const int growb = r0 + wm * 32 + m * 16 + crow0;
#pragma unroll
        for (int n = 0; n < 4; ++n) {
            const int gcol = wn * 64 + n * 16 + ccol;
            const float bv = bias[gcol] + pe[p * 128 + gcol];
#pragma unroll
            for (int j = 0; j < 4; ++j) {
                const int grow = growb + j;
                const float v = acc[m][n][j] + bv;
                C[(size_t)grow * 128 + gcol] = v;
                Cb[(size_t)grow * 128 + gcol] = f2bf(v);
            }
        }
    }
}

// ---------------------------------------------------------------------------
// bf16 MFMA GEMM, BM x BN tile (verified).
// ---------------------------------------------------------------------------
template <int BM, int BN>
__global__ __launch_bounds__(256) void k_gemm_bf16(
    const ushort* __restrict__ A, int lda,
    const ushort* __restrict__ Wt, int K,
    const float* __restrict__ bias,
    float* __restrict__ C, ushort* __restrict__ Cb, int ldc,
    const float* __restrict__ pe, int relu)
{
    constexpr int NWN = BN / 64;
    constexpr int NWM = 4 / NWN;
    constexpr int WTM = BM / NWM;
    constexpr int MF = WTM / 16;
    __shared__ ushort As[BM * 64];
    __shared__ ushort Ws[BN * 64];
    const int t = threadIdx.x;
    const int w = t >> 6, l = t & 63;
    const int r0 = blockIdx.x * BM;
    const int n0 = blockIdx.y * BN;
    const int wm = w / NWN, wn = w % NWN;
    const int lrow = l & 15, lk = l >> 4;

    f32x4 acc[MF][4];
#pragma unroll
    for (int m = 0; m < MF; ++m)
#pragma unroll
        for (int n = 0; n < 4; ++n) acc[m][n] = (f32x4)0.f;

    for (int kc = 0; kc < K; kc += 64) {
        __syncthreads();
#pragma unroll
        for (int i = t; i < BM * 8; i += 256) {
            const int row = i >> 3, ch = i & 7;
            const int sw = (ch * 16) ^ ((row & 7) << 4);
            *(short8*)((char*)As + row * 128 + sw) =
                *(const short8*)(A + (size_t)(r0 + row) * lda + kc + ch * 8);
        }
#pragma unroll
        for (int i = t; i < BN * 8; i += 256) {
            const int row = i >> 3, ch = i & 7;
            const int sw = (ch * 16) ^ ((row & 7) << 4);
            *(short8*)((char*)Ws + row * 128 + sw) =
                *(const short8*)(Wt + (size_t)(n0 + row) * K + kc + ch * 8);
        }
        __syncthreads();
#pragma unroll
        for (int ks = 0; ks < 2; ++ks) {
            bf16x8 af[MF], bfr[4];
#pragma unroll
            for (int m = 0; m < MF; ++m) {
                const int row = wm * WTM + m * 16 + lrow;
                const int col = (ks * 64 + lk * 16) ^ ((row & 7) << 4);
                af[m] = *(const bf16x8*)((const char*)As + row * 128 + col);
            }
#pragma unroll
            for (int n = 0; n < 4; ++n) {
                const int row = wn * 64 + n * 16 + lrow;
                const int col = (ks * 64 + lk * 16) ^ ((row & 7) << 4);
                bfr[n] = *(const bf16x8*)((const char*)Ws + row * 128 + col);
            }
#pragma unroll
            for (int m = 0; m < MF; ++m)
#pragma unroll
                for (int n = 0; n < 4; ++n)
                    acc[m][n] = __builtin_amdgcn_mfma_f32_16x16x32_bf16(
                        af[m], bfr[n], acc[m][n], 0, 0, 0);
        }
    }

    const int crow0 = (l >> 4) * 4;
    const int ccol = l & 15;
#pragma unroll
    for (int m = 0; m < MF; ++m) {
        const int growb = r0 + wm * WTM + m * 16 + crow0;
#pragma unroll
        for (int n = 0; n < 4; ++n) {
            const int gcol = n0 + wn * 64 + n * 16 + ccol;
            const float bv = bias[gcol];
#pragma unroll
            for (int j = 0; j < 4; ++j) {
                const int grow = growb + j;
                float v = acc[m][n][j] + bv;
                if (pe) v += pe[(grow >> 8) * 128 + gcol];
                if (relu) v = fmaxf(v, 0.f);
                if (C)  C[(size_t)grow * ldc + gcol] = v;
                if (Cb) Cb[(size_t)grow * ldc + gcol] = f2bf(v);
            }
        }
    }
}

// ---------------------------------------------------------------------------
// bf16 MFMA GEMM 64x128 + residual + LayerNorm fused epilogue (verified r5).
// ---------------------------------------------------------------------------
__global__ __launch_bounds__(256) void k_gemm_ln(
    const ushort* __restrict__ A, int lda,
    const ushort* __restrict__ Wt, int K,
    const float* __restrict__ bias,
    const float* __restrict__ resid,
    const float* __restrict__ lns, const float* __restrict__ lnbi,
    float* __restrict__ Co, ushort* __restrict__ Cb)
{
    __shared__ ushort As[64 * 64];
    __shared__ ushort Ws[128 * 64];
    __shared__ float psum[64][2][2];
    const int t = threadIdx.x;
    const int w = t >> 6, l = t & 63;
    const int r0 = blockIdx.x * 64;
    const int wm = w >> 1, wn = w & 1;
    const int lrow = l & 15, lk = l >> 4;

    f32x4 acc[2][4];
#pragma unroll
    for (int m = 0; m < 2; ++m)
#pragma unroll
        for (int n = 0; n < 4; ++n) acc[m][n] = (f32x4)0.f;

    for (int kc = 0; kc < K; kc += 64) {
        __syncthreads();
#pragma unroll
        for (int i = t; i < 64 * 8; i += 256) {
            const int row = i >> 3, ch = i & 7;
            const int sw = (ch * 16) ^ ((row & 7) << 4);
            *(short8*)((char*)As + row * 128 + sw) =
                *(const short8*)(A + (size_t)(r0 + row) * lda + kc + ch * 8);
        }
#pragma unroll
        for (int i = t; i < 128 * 8; i += 256) {
            const int row = i >> 3, ch = i & 7;
            const int sw = (ch * 16) ^ ((row & 7) << 4);
            *(short8*)((char*)Ws + row * 128 + sw) =
                *(const short8*)(Wt + (size_t)row * K + kc + ch * 8);
        }
        __syncthreads();
#pragma unroll
        for (int ks = 0; ks < 2; ++ks) {
            bf16x8 af[2], bfr[4];
#pragma unroll
            for (int m = 0; m < 2; ++m) {
                const int row = wm * 32 + m * 16 + lrow;
                const int col = (ks * 64 + lk * 16) ^ ((row & 7) << 4);
                af[m] = *(const bf16x8*)((const char*)As + row * 128 + col);
            }
#pragma unroll
            for (int n = 0; n < 4; ++n) {
                const int row = wn * 64 + n * 16 + lrow;
                const int col = (ks * 64 + lk * 16) ^ ((row & 7) << 4);
                bfr[n] = *(const bf16x8*)((const char*)Ws + row * 128 + col);
            }
#pragma unroll
            for (int m = 0; m < 2; ++m)
#pragma unroll
                for (int n = 0; n < 4; ++n)
                    acc[m][n] = __builtin_amdgcn_mfma_f32_16x16x32_bf16(
                        af[m], bfr[n], acc[m][n], 0, 0, 0);
        }
    }

    const int crow0 = (l >> 4) * 4;
    const int ccol = l & 15;
#pragma unroll
    for (int m = 0; m < 2; ++m) {
        const int growb = r0 + wm * 32 + m * 16 + crow0;
#pragma unroll
        for (int n = 0; n < 4; ++n) {
            const int gcol = wn * 64 + n * 16 + ccol;
            const float bv = bias[gcol];
#pragma unroll
            for (int j = 0; j < 4; ++j) {
                float v = acc[m][n][j] + bv;
                if (resid) v += resid[(size_t)(growb + j) * 128 + gcol];
                acc[m][n][j] = v;
            }
        }
    }
#pragma unroll
    for (int m = 0; m < 2; ++m)
#pragma unroll
        for (int j = 0; j < 4; ++j) {
            float s_ = 0.f, q_ = 0.f;
#pragma unroll
            for (int n = 0; n < 4; ++n) {
                const float x = acc[m][n][j];
                s_ += x; q_ += x * x;
            }
#pragma unroll
            for (int mk = 1; mk < 16; mk <<= 1) {
                s_ += __shfl_xor(s_, mk, 64);
                q_ += __shfl_xor(q_, mk, 64);
            }
            if (ccol == 0) {
                const int r = wm * 32 + m * 16 + crow0 + j;
                psum[r][wn][0] = s_;
                psum[r][wn][1] = q_;
            }
        }
    __syncthreads();
    float mean_[2][4], rstd_[2][4];
#pragma unroll
    for (int m = 0; m < 2; ++m)
#pragma unroll
        for (int j = 0; j < 4; ++j) {
            const int r = wm * 32 + m * 16 + crow0 + j;
            const float sum = psum[r][0][0] + psum[r][1][0];
            const float sq  = psum[r][0][1] + psum[r][1][1];
            const float mean = sum * 0.0078125f;
            const float var = sq * 0.0078125f - mean * mean;
            mean_[m][j] = mean;
            rstd_[m][j] = rsqrtf(var + 1e-5f);
        }
#pragma unroll
    for (int m = 0; m < 2; ++m) {
        const int growb = r0 + wm * 32 + m * 16 + crow0;
#pragma unroll
        for (int n = 0; n < 4; ++n) {
            const int gcol = wn * 64 + n * 16 + ccol;
            const float sv = lns[gcol], bv2 = lnbi[gcol];
#pragma unroll
            for (int j = 0; j < 4; ++j) {
                const float y = (acc[m][n][j] - mean_[m][j]) * rstd_[m][j] * sv + bv2;
                const size_t oi = (size_t)(growb + j) * 128 + gcol;
                if (Co) Co[oi] = y;
                if (Cb) Cb[oi] = f2bf(y);
            }
        }
    }
}

// ---------------------------------------------------------------------------
// MFMA flash attention, encoder self-attn (verified r3).
// ---------------------------------------------------------------------------
__global__ __launch_bounds__(256) void k_attn_mfma(
    const ushort* __restrict__ qkv, ushort* __restrict__ ob, float scale)
{
    __shared__ ushort Ks[208 * 40];
    __shared__ ushort Vt[32 * 232];
    __shared__ ushort Ps[4][16 * 232];
    const int bh = blockIdx.x;
    const int b = bh >> 2, h = bh & 3;
    const int t = threadIdx.x, w = t >> 6, l = t & 63;
    const int lr = l & 15, lg = l >> 4;

    for (int idx = t; idx < 784; idx += 256) {
        const int j = idx >> 2, ch = idx & 3;
        const size_t base = ((size_t)j * 256 + b) * 384 + h * 32 + ch * 8;
        *(short8*)(Ks + j * 40 + ch * 8) = *(const short8*)(qkv + base + 128);
        short8 v = *(const short8*)(qkv + base + 256);
#pragma unroll
        for (int q = 0; q < 8; ++q)
            Vt[(ch * 8 + q) * 232 + j] = (ushort)v[q];
    }
    for (int idx = t; idx < 32 * 36; idx += 256)
        Vt[(idx / 36) * 232 + 196 + (idx % 36)] = 0;
    for (int i = l; i < 256; i += 64)
        Ps[w][(i >> 4) * 232 + 208 + (i & 15)] = 0;
    __syncthreads();

    for (int qt = w; qt < 13; qt += 4) {
        int qr = qt * 16 + lr; if (qr > 195) qr = 195;
        const bf16x8 qf = *(const bf16x8*)(qkv + ((size_t)qr * 256 + b) * 384 + h * 32 + lg * 8);

        f32x4 s[13];
#pragma unroll
        for (int jn = 0; jn < 13; ++jn) {
            const bf16x8 kf = *(const bf16x8*)(Ks + (jn * 16 + lr) * 40 + lg * 8);
            s[jn] = __builtin_amdgcn_mfma_f32_16x16x32_bf16(qf, kf, (f32x4)0.f, 0, 0, 0);
        }
        if (lr >= 4) {
            s[12][0] = -3.0e38f; s[12][1] = -3.0e38f;
            s[12][2] = -3.0e38f; s[12][3] = -3.0e38f;
        }

        float inv[4];
        ushort* pw = Ps[w];
#pragma unroll
        for (int j = 0; j < 4; ++j) {
            float m = s[0][j];
#pragma unroll
            for (int jn = 1; jn < 13; ++jn) m = fmaxf(m, s[jn][j]);
            m = fmaxf(m, __shfl_xor(m, 1, 64));
            m = fmaxf(m, __shfl_xor(m, 2, 64));
            m = fmaxf(m, __shfl_xor(m, 4, 64));
            m = fmaxf(m, __shfl_xor(m, 8, 64));
            float sum = 0.f;
#pragma unroll
            for (int jn = 0; jn < 13; ++jn) {
                const float p = __expf((s[jn][j] - m) * scale);
                s[jn][j] = p;
                sum += p;
            }
            sum += __shfl_xor(sum, 1, 64);
            sum += __shfl_xor(sum, 2, 64);
            sum += __shfl_xor(sum, 4, 64);
            sum += __shfl_xor(sum, 8, 64);
            inv[j] = 1.0f / sum;
        }
#pragma unroll
        for (int jn = 0; jn < 13; ++jn)
#pragma unroll
            for (int j = 0; j < 4; ++j)
                pw[(lg * 4 + j) * 232 + jn * 16 + lr] = f2bf(s[jn][j]);

        f32x4 o0 = (f32x4)0.f, o1 = (f32x4)0.f;
#pragma unroll
        for (int kt = 0; kt < 7; ++kt) {
            const bf16x8 pf = *(const bf16x8*)(pw + lr * 232 + kt * 32 + lg * 8);
            const bf16x8 v0 = *(const bf16x8*)(Vt + lr * 232 + kt * 32 + lg * 8);
            const bf16x8 v1 = *(const bf16x8*)(Vt + (16 + lr) * 232 + kt * 32 + lg * 8);
            o0 = __builtin_amdgcn_mfma_f32_16x16x32_bf16(pf, v0, o0, 0, 0, 0);
            o1 = __builtin_amdgcn_mfma_f32_16x16x32_bf16(pf, v1, o1, 0, 0, 0);
        }
#pragma unroll
        for (int j = 0; j < 4; ++j) {
            const int r = qt * 16 + lg * 4 + j;
            if (r < 196) {
                const size_t o = ((size_t)r * 256 + b) * 128 + h * 32;
                ob[o + lr]      = f2bf(o0[j] * inv[j]);
                ob[o + 16 + lr] = f2bf(o1[j] * inv[j]);
            }
        }
    }
}

// ---------------------------------------------------------------------------
// Fused attention (f32, decoder cross path; verified r1).
// ---------------------------------------------------------------------------
__global__ __launch_bounds__(256) void k_attn(
    const float* __restrict__ qp, int qstride,
    const float* __restrict__ kvp, int kvstride, int koff, int voff,
    float* __restrict__ op, ushort* __restrict__ ob,
    int Lq, int Lk, float scale)
{
    __shared__ float Kl[196 * 36];
    __shared__ float Vl[196 * 32];
    __shared__ float pbuf[4][256];
    const int bh = blockIdx.x;
    const int b = bh >> 2;
    const int h = bh & 3;
    const int t = threadIdx.x;
    const int w = t >> 6;
    const int l = t & 63;

    for (int idx = t; idx < Lk * 8; idx += 256) {
        const int j = idx >> 3;
        const int kq = idx & 7;
        const size_t row = ((size_t)j * 256 + b) * kvstride + h * 32 + kq * 4;
        *(float4*)(&Kl[j * 36 + kq * 4]) = *(const float4*)(kvp + row + koff);
        *(float4*)(&Vl[j * 32 + kq * 4]) = *(const float4*)(kvp + row + voff);
    }
    if ((Lk & 1) && t < 8) *(float4*)(&Vl[Lk * 32 + t * 4]) = make_float4(0.f, 0.f, 0.f, 0.f);
    __syncthreads();

    const int Lh = (Lk + 1) >> 1;
    const int half = l >> 5;
    const int kk = l & 31;
    const int jb = half * Lh;

    for (int jq = w; jq < Lq; jq += 4) {
        const float* qrow = qp + ((size_t)jq * 256 + b) * qstride + h * 32;
        float4 q4[8];
#pragma unroll
        for (int kq = 0; kq < 8; ++kq) q4[kq] = *(const float4*)(qrow + kq * 4);

        float s[4];
#pragma unroll
        for (int r = 0; r < 4; ++r) {
            const int j = l + (r << 6);
            float acc = -3.0e38f;
            if (j < Lk) {
                acc = 0.f;
#pragma unroll
                for (int kq = 0; kq < 8; ++kq) {
                    const float4 kv = *(const float4*)(&Kl[j * 36 + kq * 4]);
                    acc += q4[kq].x * kv.x + q4[kq].y * kv.y +
                           q4[kq].z * kv.z + q4[kq].w * kv.w;
                }
                acc *= scale;
            }
            s[r] = acc;
        }
        float m = fmaxf(fmaxf(s[0], s[1]), fmaxf(s[2], s[3]));
        m = wred_max(m);
        float sum = 0.f;
#pragma unroll
        for (int r = 0; r < 4; ++r) {
            const int j = l + (r << 6);
            float p = __expf(s[r] - m);
            if (j >= Lk) p = 0.f;
            pbuf[w][j] = p;
            sum += p;
        }
        sum = wred_sum(sum);
        const float inv = 1.0f / sum;
        __threadfence_block();

        float o = 0.f;
        for (int jj = 0; jj < Lh; ++jj) {
            const float pv = pbuf[w][jb + jj];
            const float vv = Vl[(jb + jj) * 32 + kk];
            o += pv * vv;
        }
        o += __shfl_xor(o, 32, 64);
        o *= inv;
        if (l < 32) {
            const size_t oi = ((size_t)jq * 256 + b) * 128 + h * 32 + l;
            if (op) op[oi] = o;
            if (ob) ob[oi] = f2bf(o);
        }
        __threadfence_block();
    }
}

// ---------------------------------------------------------------------------
// Fused decoder part 1 v2 (512 threads, one block per batch b):
// sketch MLP -> tgt; self QKV (384 lanes); self-attn (4 head-waves);
// out-proj + resid (4-row-parallel); LN1 (8 waves) -> TGo, tg; cross-Q.
// ---------------------------------------------------------------------------
__global__ __launch_bounds__(512) void k_dec1(
    const float* __restrict__ sk,
    const float* __restrict__ W1, const float* __restrict__ b1,
    const float* __restrict__ W2, const float* __restrict__ b2,
    const float* __restrict__ W3, const float* __restrict__ b3,
    const float* __restrict__ ang, const float* __restrict__ px,
    const float* __restrict__ py,
    const float* __restrict__ actW, const float* __restrict__ actb,
    const float* __restrict__ saW, const float* __restrict__ sab,
    const float* __restrict__ saoW, const float* __restrict__ saob,
    const float* __restrict__ ln1s, const float* __restrict__ ln1b,
    const float* __restrict__ caW, const float* __restrict__ cab,
    float* __restrict__ TGo, float* __restrict__ DQ)
{
    __shared__ float tg[15][128];
    __shared__ float qkv[15][388];   // +4 pad
    __shared__ float ao[15][128];
    __shared__ float xr[256], h1[256], h2[256];
    __shared__ float s3[100];
    __shared__ float pbv[4][16];
    const int b = blockIdx.x, t = threadIdx.x;
    const int w = t >> 6, l = t & 63;

    // sketch MLP (first 256 threads; serial chains are short)
    if (t < 256) xr[t] = (t < 200) ? sk[(size_t)b * 200 + t] : 0.f;
    __syncthreads();
    if (t < 256) {
        float a = b1[t];
        for (int k = 0; k < 200; ++k) a += xr[k] * W1[k * 256 + t];
        h1[t] = fmaxf(a, 0.f);
    }
    __syncthreads();
    if (t < 256) {
        float a = b2[t];
        for (int k = 0; k < 256; ++k) a += h1[k] * W2[k * 256 + t];
        h2[t] = fmaxf(a, 0.f);
    }
    __syncthreads();
    if (t < 100) {
        float a = b3[t];
        for (int k = 0; k < 256; ++k) a += h2[k] * W3[k * 100 + t];
        s3[t] = a;
    }
    __syncthreads();
    if (t < 128) {
        float base = actb[t] + ang[b] * actW[15 * 128 + t] +
                     px[b] * actW[16 * 128 + t] + py[b] * actW[17 * 128 + t];
        for (int k = 0; k < 100; ++k) base += s3[k] * actW[(18 + k) * 128 + t];
#pragma unroll
        for (int i = 0; i < 15; ++i) tg[i][t] = base + actW[i * 128 + t];
    }
    __syncthreads();

    // self QKV: 384 lanes, 15 rows in regs (15-way ILP)
    if (t < 384) {
        float acc[15];
#pragma unroll
        for (int r = 0; r < 15; ++r) acc[r] = 0.f;
        for (int k = 0; k < 128; ++k) {
            const float wv = saW[(size_t)k * 384 + t];
#pragma unroll
            for (int r = 0; r < 15; ++r) acc[r] += tg[r][k] * wv;
        }
        const float bb = sab[t];
#pragma unroll
        for (int r = 0; r < 15; ++r) qkv[r][t] = acc[r] + bb;
    }
    __syncthreads();

    // self-attn: waves 0..3 = heads
    const float rs = 0.17677669529663687f;
    if (w < 4) {
        for (int qi = 0; qi < 15; ++qi) {
            float s = -3.0e38f;
            if (l < 15) {
                s = 0.f;
                for (int d = 0; d < 32; ++d)
                    s += qkv[qi][w * 32 + d] * qkv[l][128 + w * 32 + d];
                s *= rs;
            }
            const float m = wred_max(s);
            const float pv = (l < 15) ? __expf(s - m) : 0.f;
            const float sum = wred_sum(pv);
            if (l < 15) pbv[w][l] = pv;
            if (l < 32) {
                float o = 0.f;
#pragma unroll
                for (int j = 0; j < 15; ++j) o += pbv[w][j] * qkv[j][256 + w * 32 + l];
                ao[qi][w * 32 + l] = o / sum;
            }
        }
    }
    __syncthreads();

    // SA out-proj + residual (4 rows in parallel across thread groups)
    {
        const int c = t & 127, r0 = t >> 7;   // r0 in 0..3
        for (int r = r0; r < 15; r += 4) {
            float acc = saob[c] + tg[r][c];
            for (int k = 0; k < 128; ++k) acc += ao[r][k] * saoW[(size_t)k * 128 + c];
            qkv[r][c] = acc;
        }
    }
    __syncthreads();
    // LN1 (8 waves) -> tg + TGo
    for (int r = w; r < 15; r += 8) {
        const float x0 = qkv[r][l], x1 = qkv[r][l + 64];
        const float sm = wred_sum(x0 + x1);
        const float sq = wred_sum(x0 * x0 + x1 * x1);
        const float mean = sm * 0.0078125f;
        const float rstd = rsqrtf(sq * 0.0078125f - mean * mean + 1e-5f);
        const float y0 = (x0 - mean) * rstd * ln1s[l] + ln1b[l];
        const float y1 = (x1 - mean) * rstd * ln1s[l + 64] + ln1b[l + 64];
        tg[r][l] = y0; tg[r][l + 64] = y1;
        float* g = TGo + ((size_t)r * 256 + b) * 128;
        g[l] = y0; g[l + 64] = y1;
    }
    __syncthreads();

    // cross Q (4 rows parallel)
    {
        const int c = t & 127, r0 = t >> 7;
        for (int r = r0; r < 15; r += 4) {
            float acc = cab[c];
            for (int k = 0; k < 128; ++k) acc += tg[r][k] * caW[(size_t)k * 384 + c];
            DQ[((size_t)r * 256 + b) * 128 + c] = acc;
        }
    }
}

// ---------------------------------------------------------------------------
// Fused decoder part 2 v2 (512 threads, one block per batch b):
// cross-out + resid + LN2; FF1; FF2 + resid + LN3; dec_norm; l1 + head dot.
// ---------------------------------------------------------------------------
__global__ __launch_bounds__(512) void k_dec2(
    const float* __restrict__ TGo, const float* __restrict__ AT,
    const float* __restrict__ caoW, const float* __restrict__ caob,
    const float* __restrict__ ln2s, const float* __restrict__ ln2b,
    const float* __restrict__ ff1W, const float* __restrict__ ff1b,
    const float* __restrict__ ff2W, const float* __restrict__ ff2b,
    const float* __restrict__ ln3s, const float* __restrict__ ln3b,
    const float* __restrict__ ns, const float* __restrict__ nb,
    const float* __restrict__ l1W, const float* __restrict__ l1b,
    const float* __restrict__ l2w, const float* __restrict__ l2b,
    float* __restrict__ qout)
{
    __shared__ float tg[15][128], ao[15][128], o2[15][128];
    __shared__ float ff[15][64];
    const int b = blockIdx.x, t = threadIdx.x;
    const int w = t >> 6, l = t & 63;

    for (int idx = t; idx < 1920; idx += 512) {
        const int r = idx >> 7, c = idx & 127;
        tg[r][c] = TGo[((size_t)r * 256 + b) * 128 + c];
        ao[r][c] = AT[((size_t)r * 256 + b) * 128 + c];
    }
    __syncthreads();

    // CA out-proj + residual (4 rows parallel)
    {
        const int c = t & 127, r0 = t >> 7;
        for (int r = r0; r < 15; r += 4) {
            float acc = caob[c] + tg[r][c];
            for (int k = 0; k < 128; ++k) acc += ao[r][k] * caoW[(size_t)k * 128 + c];
            o2[r][c] = acc;
        }
    }
    __syncthreads();
    // LN2 (8 waves) -> tg
    for (int r = w; r < 15; r += 8) {
        const float x0 = o2[r][l], x1 = o2[r][l + 64];
        const float sm = wred_sum(x0 + x1);
        const float sq = wred_sum(x0 * x0 + x1 * x1);
        const float mean = sm * 0.0078125f;
        const float rstd = rsqrtf(sq * 0.0078125f - mean * mean + 1e-5f);
        tg[r][l]      = (x0 - mean) * rstd * ln2s[l] + ln2b[l];
        tg[r][l + 64] = (x1 - mean) * rstd * ln2s[l + 64] + ln2b[l + 64];
    }
    __syncthreads();
    // FF1 (relu): 8 groups of 64 cols
    {
        const int n = t & 63, r0 = t >> 6;   // r0 in 0..7
        for (int r = r0; r < 15; r += 8) {
            float acc = ff1b[n];
            for (int k = 0; k < 128; ++k) acc += tg[r][k] * ff1W[(size_t)k * 64 + n];
            ff[r][n] = fmaxf(acc, 0.f);
        }
    }
    __syncthreads();
    // FF2 + residual (4 rows parallel)
    {
        const int c = t & 127, r0 = t >> 7;
        for (int r = r0; r < 15; r += 4) {
            float acc = ff2b[c] + tg[r][c];
            for (int k = 0; k < 64; ++k) acc += ff[r][k] * ff2W[(size_t)k * 128 + c];
            o2[r][c] = acc;
        }
    }
    __syncthreads();
    // LN3 then dec_norm (8 waves) -> tg
    for (int r = w; r < 15; r += 8) {
        const float x0 = o2[r][l], x1 = o2[r][l + 64];
        const float sm = wred_sum(x0 + x1);
        const float sq = wred_sum(x0 * x0 + x1 * x1);
        const float mean = sm * 0.0078125f;
        const float rstd = rsqrtf(sq * 0.0078125f - mean * mean + 1e-5f);
        const float y0 = (x0 - mean) * rstd * ln3s[l] + ln3b[l];
        const float y1 = (x1 - mean) * rstd * ln3s[l + 64] + ln3b[l + 64];
        const float sm2 = wred_sum(y0 + y1);
        const float sq2 = wred_sum(y0 * y0 + y1 * y1);
        const float mean2 = sm2 * 0.0078125f;
        const float rstd2 = rsqrtf(sq2 * 0.0078125f - mean2 * mean2 + 1e-5f);
        tg[r][l]      = (y0 - mean2) * rstd2 * ns[l] + nb[l];
        tg[r][l + 64] = (y1 - mean2) * rstd2 * ns[l + 64] + nb[l + 64];
    }
    __syncthreads();
    // l1 (relu, 4 rows parallel)
    {
        const int c = t & 127, r0 = t >> 7;
        for (int r = r0; r < 15; r += 4) {
            float acc = l1b[c];
            for (int k = 0; k < 128; ++k) acc += tg[r][k] * l1W[(size_t)k * 128 + c];
            o2[r][c] = fmaxf(acc, 0.f);
        }
    }
    __syncthreads();
    // head dot (8 waves)
    for (int r = w; r < 15; r += 8) {
        const float d = wred_sum(o2[r][l] * l2w[l] + o2[r][l + 64] * l2w[l + 64]);
        if (l == 0) qout[b * 15 + r] = d + l2b[0];
    }
}

// ---------------------------------------------------------------------------
extern "C" void kernel_launch(void* const* d_in, const int* in_sizes, int n_in,
                              void* d_out, int out_size, void* d_ws, size_t ws_size,
                              hipStream_t stream)
{
    (void)in_sizes; (void)n_in; (void)out_size; (void)ws_size;
    const float* image      = (const float*)d_in[0];
    const float* angle      = (const float*)d_in[1];
    const float* pos_x      = (const float*)d_in[2];
    const float* pos_y      = (const float*)d_in[3];
    const float* sk         = (const float*)d_in[4];
    const float* patch_W    = (const float*)d_in[5];
    const float* patch_b    = (const float*)d_in[6];
    const float* pos_emb    = (const float*)d_in[7];
    const float* enc_qkv_W  = (const float*)d_in[8];
    const float* enc_qkv_b  = (const float*)d_in[9];
    const float* enc_out_W  = (const float*)d_in[10];
    const float* enc_out_b  = (const float*)d_in[11];
    const float* enc_ln1_s  = (const float*)d_in[12];
    const float* enc_ln1_b  = (const float*)d_in[13];
    const float* enc_ff1_W  = (const float*)d_in[14];
    const float* enc_ff1_b  = (const float*)d_in[15];
    const float* enc_ff2_W  = (const float*)d_in[16];
    const float* enc_ff2_b  = (const float*)d_in[17];
    const float* enc_ln2_s  = (const float*)d_in[18];
    const float* enc_ln2_b  = (const float*)d_in[19];
    const float* dec_sa_qkv_W = (const float*)d_in[20];
    const float* dec_sa_qkv_b = (const float*)d_in[21];
    const float* dec_sa_out_W = (const float*)d_in[22];
    const float* dec_sa_out_b = (const float*)d_in[23];
    const float* dec_ca_qkv_W = (const float*)d_in[24];
    const float* dec_ca_qkv_b = (const float*)d_in[25];
    const float* dec_ca_out_W = (const float*)d_in[26];
    const float* dec_ca_out_b = (const float*)d_in[27];
    const float* dec_ln1_s  = (const float*)d_in[28];
    const float* dec_ln1_b  = (const float*)d_in[29];
    const float* dec_ln2_s  = (const float*)d_in[30];
    const float* dec_ln2_b  = (const float*)d_in[31];
    const float* dec_ln3_s  = (const float*)d_in[32];
    const float* dec_ln3_b  = (const float*)d_in[33];
    const float* dec_ff1_W  = (const float*)d_in[34];
    const float* dec_ff1_b  = (const float*)d_in[35];
    const float* dec_ff2_W  = (const float*)d_in[36];
    const float* dec_ff2_b  = (const float*)d_in[37];
    const float* dec_norm_s = (const float*)d_in[38];
    const float* dec_norm_b = (const float*)d_in[39];
    const float* sk1_W = (const float*)d_in[40];
    const float* sk1_b = (const float*)d_in[41];
    const float* sk2_W = (const float*)d_in[42];
    const float* sk2_b = (const float*)d_in[43];
    const float* sk3_W = (const float*)d_in[44];
    const float* sk3_b = (const float*)d_in[45];
    const float* act_W = (const float*)d_in[46];
    const float* act_b = (const float*)d_in[47];
    const float* l1_W  = (const float*)d_in[48];
    const float* l1_b  = (const float*)d_in[49];
    const float* l2_W  = (const float*)d_in[50];
    const float* l2_b  = (const float*)d_in[51];

    // Workspace (float offsets)
    float* ws = (float*)d_ws;
    float* S0   = ws;               // src f32 residual stream  [6,422,528]
    float* QKVr = ws + 6422528;     // big overlay region       [19,267,584]
    float* T0   = ws + 25690112;    // decoder cross-attn out   [6,422,528]
    float* T1   = ws + 32112640;    // M0b bf16 home            [6,422,528]
    float* F1   = ws + 38535168;    // F1b bf16                 [3,211,264]
    float* M0r  = ws + 41746432;    // srcb/T0b | lnb bf16      [6,422,528]
    float* S1s  = ws + 48168960;
    float* TG   = S1s + 156672;     // tgt f32 15*256*128
    ushort* WTS = (ushort*)(ws + 48817152);

    // Overlays
    ushort* QKVb = (ushort*)QKVr;            // enc QKV bf16 [50176][384]
    float*  KV   = QKVr;                     // cross K/V f32 [50176][256]
    float* DQ   = QKVr + 14319616;           // dec cross Q f32
    float* DT0  = T0;
    ushort* srcb = (ushort*)M0r;
    ushort* T0b  = (ushort*)M0r;             // disjoint lifetime with srcb
    ushort* lnb  = (ushort*)(M0r + 3211264);
    ushort* F1b  = (ushort*)F1;
    ushort* M0b  = (ushort*)T1;
    ushort* wt_patch = WTS;
    ushort* wt_qkv   = WTS + 98304;
    ushort* wt_out   = WTS + 147456;
    ushort* wt_ff1   = WTS + 163840;
    ushort* wt_ff2   = WTS + 172032;
    ushort* wt_ckv   = WTS + 180224;

    const float rs = 0.17677669529663687f;  // 1/sqrt(32)

    // ---- prep ----
    k_wconv<<<dim3(832), 256, 0, stream>>>(patch_W, enc_qkv_W, enc_out_W,
                                           enc_ff1_W, enc_ff2_W, dec_ca_qkv_W, WTS);
    k_dec1<<<dim3(256), 512, 0, stream>>>(
        sk, sk1_W, sk1_b, sk2_W, sk2_b, sk3_W, sk3_b,
        angle, pos_x, pos_y, act_W, act_b,
        dec_sa_qkv_W, dec_sa_qkv_b, dec_sa_out_W, dec_sa_out_b,
        dec_ln1_s, dec_ln1_b, dec_ca_qkv_W, dec_ca_qkv_b, TG, DQ);

    // ---- encoder ----
    k_pgemm<<<dim3(784), 256, 0, stream>>>(
        image, wt_patch, patch_b, pos_emb, S0, srcb);
    k_gemm_bf16<64, 128><<<dim3(784, 3), 256, 0, stream>>>(
        srcb, 128, wt_qkv, 128, enc_qkv_b, nullptr, QKVb, 384, nullptr, 0);
    k_attn_mfma<<<dim3(1024), 256, 0, stream>>>(QKVb, T0b, rs);
    k_gemm_ln<<<dim3(784), 256, 0, stream>>>(                 // out-proj + LN1
        T0b, 128, wt_out, 128, enc_out_b, S0, enc_ln1_s, enc_ln1_b, S0, lnb);
    k_gemm_bf16<64, 64><<<dim3(784, 1), 256, 0, stream>>>(    // FF1 + relu
        lnb, 128, wt_ff1, 128, enc_ff1_b, nullptr, F1b, 64, nullptr, 1);
    k_gemm_ln<<<dim3(784), 256, 0, stream>>>(                 // FF2 + LN2
        F1b, 64, wt_ff2, 64, enc_ff2_b, S0, enc_ln2_s, enc_ln2_b, nullptr, M0b);
    k_gemm_bf16<64, 128><<<dim3(784, 2), 256, 0, stream>>>(   // cross K/V
        M0b, 128, wt_ckv, 128, dec_ca_qkv_b + 128, KV, nullptr, 256, nullptr, 0);

    // ---- decoder cross-attn + tail ----
    k_attn<<<dim3(1024), 256, 0, stream>>>(DQ, 128, KV, 256, 0, 128,
                                           DT0, nullptr, 15, 196, rs);
    k_dec2<<<dim3(256), 512, 0, stream>>>(
        TG, DT0, dec_ca_out_W, dec_ca_out_b, dec_ln2_s, dec_ln2_b,
        dec_ff1_W, dec_ff1_b, dec_ff2_W, dec_ff2_b,
        dec_ln3_s, dec_ln3_b, dec_norm_s, dec_norm_b,
        l1_W, l1_b, l2_W, l2_b, (float*)d_out);
}

// Round 9
// 392.072 us; speedup vs baseline: 1.2179x; 1.0285x over previous
//
#include <hip/hip_runtime.h>
#include <math.h>

#define BSZ 256
#define DIM 128
#define NHD 4
#define NPATCH 196
#define NACT 15

typedef float f32x4 __attribute__((ext_vector_type(4)));
typedef __bf16 bf16x8 __attribute__((ext_vector_type(8)));
typedef short short8 __attribute__((ext_vector_type(8)));

__device__ __forceinline__ float wred_sum(float v) {
#pragma unroll
    for (int m = 1; m < 64; m <<= 1) v += __shfl_xor(v, m, 64);
    return v;
}
__device__ __forceinline__ float wred_max(float v) {
#pragma unroll
    for (int m = 1; m < 64; m <<= 1) v = fmaxf(v, __shfl_xor(v, m, 64));
    return v;
}
__device__ __forceinline__ ushort f2bf(float f) {  // RNE bf16
    unsigned u = __float_as_uint(f);
    return (ushort)((u + 0x7fffu + ((u >> 16) & 1u)) >> 16);
}

// ---------------------------------------------------------------------------
// Weight convert+transpose to bf16 [N][K] (patch K-permuted), packed.
// ---------------------------------------------------------------------------
__global__ __launch_bounds__(256) void k_wconv(
    const float* __restrict__ pW, const float* __restrict__ qkvW,
    const float* __restrict__ outW, const float* __restrict__ ff1W,
    const float* __restrict__ ff2W, const float* __restrict__ ckvW,
    ushort* __restrict__ o)
{
    int i = blockIdx.x * 256 + threadIdx.x;
    if (i < 98304) {
        int n = i / 768, kp = i % 768;
        int c = kp >> 8, q = kp & 255;
        o[i] = f2bf(pW[(q * 3 + c) * 128 + n]); return;
    }
    i -= 98304;
    if (i < 49152) { int n = i >> 7, k = i & 127; o[98304 + i] = f2bf(qkvW[k * 384 + n]); return; }
    i -= 49152;
    if (i < 16384) { int n = i >> 7, k = i & 127; o[147456 + i] = f2bf(outW[k * 128 + n]); return; }
    i -= 16384;
    if (i < 8192)  { int n = i >> 7, k = i & 127; o[163840 + i] = f2bf(ff1W[k * 64 + n]); return; }
    i -= 8192;
    if (i < 8192)  { int n = i >> 6, k = i & 63;  o[172032 + i] = f2bf(ff2W[k * 128 + n]); return; }
    i -= 8192;
    if (i < 32768) { int n = i >> 7, k = i & 127; o[180224 + i] = f2bf(ckvW[k * 384 + 128 + n]); return; }
}

// ---------------------------------------------------------------------------
// Fused patchify + patch-embed MFMA GEMM (verified r6).
// ---------------------------------------------------------------------------
__global__ __launch_bounds__(256) void k_pgemm(
    const float* __restrict__ img, const ushort* __restrict__ Wt,
    const float* __restrict__ bias, const float* __restrict__ pe,
    float* __restrict__ C, ushort* __restrict__ Cb)
{
    __shared__ ushort As[64 * 64];
    __shared__ ushort Ws[128 * 64];
    const int t = threadIdx.x;
    const int w = t >> 6, l = t & 63;
    const int pb = blockIdx.x;
    const int p = pb >> 2, bq = pb & 3;
    const int hp = p / 14, wp = p % 14;
    const int r0 = p * 256 + bq * 64;
    const int wm = w >> 1, wn = w & 1;
    const int lrow = l & 15, lk = l >> 4;
    const int arow = t >> 2;
    const int b_img = bq * 64 + arow;
    const float* gimg = img + (size_t)b_img * 150528 + hp * (16 * 224) + wp * 16;

    f32x4 acc[2][4];
#pragma unroll
    for (int m = 0; m < 2; ++m)
#pragma unroll
        for (int n = 0; n < 4; ++n) acc[m][n] = (f32x4)0.f;

    for (int kc = 0; kc < 768; kc += 64) {
        const int c = kc >> 8, p1q = (kc >> 6) & 3;
        const float* gc = gimg + c * 50176 + p1q * 4 * 224;
        __syncthreads();
#pragma unroll
        for (int i = 0; i < 4; ++i) {
            const int kq = (t & 3) + 4 * i;
            const int p1 = kq >> 2, p2q = kq & 3;
            const float4 v = *(const float4*)(gc + p1 * 224 + p2q * 4);
            ushort4 o4;
            o4.x = f2bf(v.x); o4.y = f2bf(v.y); o4.z = f2bf(v.z); o4.w = f2bf(v.w);
            const int bo = (kq * 8) ^ ((arow & 7) << 4);
            *(ushort4*)((char*)As + arow * 128 + bo) = o4;
        }
        for (int i2 = t; i2 < 128 * 8; i2 += 256) {
            const int row = i2 >> 3, ch = i2 & 7;
            const int sw = (ch * 16) ^ ((row & 7) << 4);
            *(short8*)((char*)Ws + row * 128 + sw) =
                *(const short8*)(Wt + (size_t)row * 768 + kc + ch * 8);
        }
        __syncthreads();
#pragma unroll
        for (int ks = 0; ks < 2; ++ks) {
            bf16x8 af[2], bfr[4];
#pragma unroll
            for (int m = 0; m < 2; ++m) {
                const int row = wm * 32 + m * 16 + lrow;
                const int col = (ks * 64 + lk * 16) ^ ((row & 7) << 4);
                af[m] = *(const bf16x8*)((const char*)As + row * 128 + col);
            }
#pragma unroll
            for (int n = 0; n < 4; ++n) {
                const int row = wn * 64 + n * 16 + lrow;
                const int col = (ks * 64 + lk * 16) ^ ((row & 7) << 4);
                bfr[n] = *(const bf16x8*)((const char*)Ws + row * 128 + col);
            }
#pragma unroll
            for (int m = 0; m < 2; ++m)
#pragma unroll
                for (int n = 0; n < 4; ++n)
                    acc[m][n] = __builtin_amdgcn_mfma_f32_16x16x32_bf16(
                        af[m], bfr[n], acc[m][n], 0, 0, 0);
        }
    }

    const int crow0 = (l >> 4) * 4;
    const int ccol = l & 15;
#pragma unroll
    for (int m = 0; m < 2; ++m) {
        const int growb = r0 + wm * 32 + m * 16 + crow0;
#pragma unroll
        for (int n = 0; n < 4; ++n) {
            const int gcol = wn * 64 + n * 16 + ccol;
            const float bv = bias[gcol] + pe[p * 128 + gcol];
#pragma unroll
            for (int j = 0; j < 4; ++j) {
                const int grow = growb + j;
                const float v = acc[m][n][j] + bv;
                C[(size_t)grow * 128 + gcol] = v;
                Cb[(size_t)grow * 128 + gcol] = f2bf(v);
            }
        }
    }
}

// ---------------------------------------------------------------------------
// bf16 MFMA GEMM, BM x BN tile (verified).
// ---------------------------------------------------------------------------
template <int BM, int BN>
__global__ __launch_bounds__(256) void k_gemm_bf16(
    const ushort* __restrict__ A, int lda,
    const ushort* __restrict__ Wt, int K,
    const float* __restrict__ bias,
    float* __restrict__ C, ushort* __restrict__ Cb, int ldc,
    const float* __restrict__ pe, int relu)
{
    constexpr int NWN = BN / 64;
    constexpr int NWM = 4 / NWN;
    constexpr int WTM = BM / NWM;
    constexpr int MF = WTM / 16;
    __shared__ ushort As[BM * 64];
    __shared__ ushort Ws[BN * 64];
    const int t = threadIdx.x;
    const int w = t >> 6, l = t & 63;
    const int r0 = blockIdx.x * BM;
    const int n0 = blockIdx.y * BN;
    const int wm = w / NWN, wn = w % NWN;
    const int lrow = l & 15, lk = l >> 4;

    f32x4 acc[MF][4];
#pragma unroll
    for (int m = 0; m < MF; ++m)
#pragma unroll
        for (int n = 0; n < 4; ++n) acc[m][n] = (f32x4)0.f;

    for (int kc = 0; kc < K; kc += 64) {
        __syncthreads();
#pragma unroll
        for (int i = t; i < BM * 8; i += 256) {
            const int row = i >> 3, ch = i & 7;
            const int sw = (ch * 16) ^ ((row & 7) << 4);
            *(short8*)((char*)As + row * 128 + sw) =
                *(const short8*)(A + (size_t)(r0 + row) * lda + kc + ch * 8);
        }
#pragma unroll
        for (int i = t; i < BN * 8; i += 256) {
            const int row = i >> 3, ch = i & 7;
            const int sw = (ch * 16) ^ ((row & 7) << 4);
            *(short8*)((char*)Ws + row * 128 + sw) =
                *(const short8*)(Wt + (size_t)(n0 + row) * K + kc + ch * 8);
        }
        __syncthreads();
#pragma unroll
        for (int ks = 0; ks < 2; ++ks) {
            bf16x8 af[MF], bfr[4];
#pragma unroll
            for (int m = 0; m < MF; ++m) {
                const int row = wm * WTM + m * 16 + lrow;
                const int col = (ks * 64 + lk * 16) ^ ((row & 7) << 4);
                af[m] = *(const bf16x8*)((const char*)As + row * 128 + col);
            }
#pragma unroll
            for (int n = 0; n < 4; ++n) {
                const int row = wn * 64 + n * 16 + lrow;
                const int col = (ks * 64 + lk * 16) ^ ((row & 7) << 4);
                bfr[n] = *(const bf16x8*)((const char*)Ws + row * 128 + col);
            }
#pragma unroll
            for (int m = 0; m < MF; ++m)
#pragma unroll
                for (int n = 0; n < 4; ++n)
                    acc[m][n] = __builtin_amdgcn_mfma_f32_16x16x32_bf16(
                        af[m], bfr[n], acc[m][n], 0, 0, 0);
        }
    }

    const int crow0 = (l >> 4) * 4;
    const int ccol = l & 15;
#pragma unroll
    for (int m = 0; m < MF; ++m) {
        const int growb = r0 + wm * WTM + m * 16 + crow0;
#pragma unroll
        for (int n = 0; n < 4; ++n) {
            const int gcol = n0 + wn * 64 + n * 16 + ccol;
            const float bv = bias[gcol];
#pragma unroll
            for (int j = 0; j < 4; ++j) {
                const int grow = growb + j;
                float v = acc[m][n][j] + bv;
                if (pe) v += pe[(grow >> 8) * 128 + gcol];
                if (relu) v = fmaxf(v, 0.f);
                if (C)  C[(size_t)grow * ldc + gcol] = v;
                if (Cb) Cb[(size_t)grow * ldc + gcol] = f2bf(v);
            }
        }
    }
}

// ---------------------------------------------------------------------------
// bf16 MFMA GEMM 64x128 + residual + LayerNorm fused epilogue (verified r5).
// ---------------------------------------------------------------------------
__global__ __launch_bounds__(256) void k_gemm_ln(
    const ushort* __restrict__ A, int lda,
    const ushort* __restrict__ Wt, int K,
    const float* __restrict__ bias,
    const float* __restrict__ resid,
    const float* __restrict__ lns, const float* __restrict__ lnbi,
    float* __restrict__ Co, ushort* __restrict__ Cb)
{
    __shared__ ushort As[64 * 64];
    __shared__ ushort Ws[128 * 64];
    __shared__ float psum[64][2][2];
    const int t = threadIdx.x;
    const int w = t >> 6, l = t & 63;
    const int r0 = blockIdx.x * 64;
    const int wm = w >> 1, wn = w & 1;
    const int lrow = l & 15, lk = l >> 4;

    f32x4 acc[2][4];
#pragma unroll
    for (int m = 0; m < 2; ++m)
#pragma unroll
        for (int n = 0; n < 4; ++n) acc[m][n] = (f32x4)0.f;

    for (int kc = 0; kc < K; kc += 64) {
        __syncthreads();
#pragma unroll
        for (int i = t; i < 64 * 8; i += 256) {
            const int row = i >> 3, ch = i & 7;
            const int sw = (ch * 16) ^ ((row & 7) << 4);
            *(short8*)((char*)As + row * 128 + sw) =
                *(const short8*)(A + (size_t)(r0 + row) * lda + kc + ch * 8);
        }
#pragma unroll
        for (int i = t; i < 128 * 8; i += 256) {
            const int row = i >> 3, ch = i & 7;
            const int sw = (ch * 16) ^ ((row & 7) << 4);
            *(short8*)((char*)Ws + row * 128 + sw) =
                *(const short8*)(Wt + (size_t)row * K + kc + ch * 8);
        }
        __syncthreads();
#pragma unroll
        for (int ks = 0; ks < 2; ++ks) {
            bf16x8 af[2], bfr[4];
#pragma unroll
            for (int m = 0; m < 2; ++m) {
                const int row = wm * 32 + m * 16 + lrow;
                const int col = (ks * 64 + lk * 16) ^ ((row & 7) << 4);
                af[m] = *(const bf16x8*)((const char*)As + row * 128 + col);
            }
#pragma unroll
            for (int n = 0; n < 4; ++n) {
                const int row = wn * 64 + n * 16 + lrow;
                const int col = (ks * 64 + lk * 16) ^ ((row & 7) << 4);
                bfr[n] = *(const bf16x8*)((const char*)Ws + row * 128 + col);
            }
#pragma unroll
            for (int m = 0; m < 2; ++m)
#pragma unroll
                for (int n = 0; n < 4; ++n)
                    acc[m][n] = __builtin_amdgcn_mfma_f32_16x16x32_bf16(
                        af[m], bfr[n], acc[m][n], 0, 0, 0);
        }
    }

    const int crow0 = (l >> 4) * 4;
    const int ccol = l & 15;
#pragma unroll
    for (int m = 0; m < 2; ++m) {
        const int growb = r0 + wm * 32 + m * 16 + crow0;
#pragma unroll
        for (int n = 0; n < 4; ++n) {
            const int gcol = wn * 64 + n * 16 + ccol;
            const float bv = bias[gcol];
#pragma unroll
            for (int j = 0; j < 4; ++j) {
                float v = acc[m][n][j] + bv;
                if (resid) v += resid[(size_t)(growb + j) * 128 + gcol];
                acc[m][n][j] = v;
            }
        }
    }
#pragma unroll
    for (int m = 0; m < 2; ++m)
#pragma unroll
        for (int j = 0; j < 4; ++j) {
            float s_ = 0.f, q_ = 0.f;
#pragma unroll
            for (int n = 0; n < 4; ++n) {
                const float x = acc[m][n][j];
                s_ += x; q_ += x * x;
            }
#pragma unroll
            for (int mk = 1; mk < 16; mk <<= 1) {
                s_ += __shfl_xor(s_, mk, 64);
                q_ += __shfl_xor(q_, mk, 64);
            }
            if (ccol == 0) {
                const int r = wm * 32 + m * 16 + crow0 + j;
                psum[r][wn][0] = s_;
                psum[r][wn][1] = q_;
            }
        }
    __syncthreads();
    float mean_[2][4], rstd_[2][4];
#pragma unroll
    for (int m = 0; m < 2; ++m)
#pragma unroll
        for (int j = 0; j < 4; ++j) {
            const int r = wm * 32 + m * 16 + crow0 + j;
            const float sum = psum[r][0][0] + psum[r][1][0];
            const float sq  = psum[r][0][1] + psum[r][1][1];
            const float mean = sum * 0.0078125f;
            const float var = sq * 0.0078125f - mean * mean;
            mean_[m][j] = mean;
            rstd_[m][j] = rsqrtf(var + 1e-5f);
        }
#pragma unroll
    for (int m = 0; m < 2; ++m) {
        const int growb = r0 + wm * 32 + m * 16 + crow0;
#pragma unroll
        for (int n = 0; n < 4; ++n) {
            const int gcol = wn * 64 + n * 16 + ccol;
            const float sv = lns[gcol], bv2 = lnbi[gcol];
#pragma unroll
            for (int j = 0; j < 4; ++j) {
                const float y = (acc[m][n][j] - mean_[m][j]) * rstd_[m][j] * sv + bv2;
                const size_t oi = (size_t)(growb + j) * 128 + gcol;
                if (Co) Co[oi] = y;
                if (Cb) Cb[oi] = f2bf(y);
            }
        }
    }
}

// ---------------------------------------------------------------------------
// MFMA flash attention, encoder self-attn (verified r3).
// ---------------------------------------------------------------------------
__global__ __launch_bounds__(256) void k_attn_mfma(
    const ushort* __restrict__ qkv, ushort* __restrict__ ob, float scale)
{
    __shared__ ushort Ks[208 * 40];
    __shared__ ushort Vt[32 * 232];
    __shared__ ushort Ps[4][16 * 232];
    const int bh = blockIdx.x;
    const int b = bh >> 2, h = bh & 3;
    const int t = threadIdx.x, w = t >> 6, l = t & 63;
    const int lr = l & 15, lg = l >> 4;

    for (int idx = t; idx < 784; idx += 256) {
        const int j = idx >> 2, ch = idx & 3;
        const size_t base = ((size_t)j * 256 + b) * 384 + h * 32 + ch * 8;
        *(short8*)(Ks + j * 40 + ch * 8) = *(const short8*)(qkv + base + 128);
        short8 v = *(const short8*)(qkv + base + 256);
#pragma unroll
        for (int q = 0; q < 8; ++q)
            Vt[(ch * 8 + q) * 232 + j] = (ushort)v[q];
    }
    for (int idx = t; idx < 32 * 36; idx += 256)
        Vt[(idx / 36) * 232 + 196 + (idx % 36)] = 0;
    for (int i = l; i < 256; i += 64)
        Ps[w][(i >> 4) * 232 + 208 + (i & 15)] = 0;
    __syncthreads();

    for (int qt = w; qt < 13; qt += 4) {
        int qr = qt * 16 + lr; if (qr > 195) qr = 195;
        const bf16x8 qf = *(const bf16x8*)(qkv + ((size_t)qr * 256 + b) * 384 + h * 32 + lg * 8);

        f32x4 s[13];
#pragma unroll
        for (int jn = 0; jn < 13; ++jn) {
            const bf16x8 kf = *(const bf16x8*)(Ks + (jn * 16 + lr) * 40 + lg * 8);
            s[jn] = __builtin_amdgcn_mfma_f32_16x16x32_bf16(qf, kf, (f32x4)0.f, 0, 0, 0);
        }
        if (lr >= 4) {
            s[12][0] = -3.0e38f; s[12][1] = -3.0e38f;
            s[12][2] = -3.0e38f; s[12][3] = -3.0e38f;
        }

        float inv[4];
        ushort* pw = Ps[w];
#pragma unroll
        for (int j = 0; j < 4; ++j) {
            float m = s[0][j];
#pragma unroll
            for (int jn = 1; jn < 13; ++jn) m = fmaxf(m, s[jn][j]);
            m = fmaxf(m, __shfl_xor(m, 1, 64));
            m = fmaxf(m, __shfl_xor(m, 2, 64));
            m = fmaxf(m, __shfl_xor(m, 4, 64));
            m = fmaxf(m, __shfl_xor(m, 8, 64));
            float sum = 0.f;
#pragma unroll
            for (int jn = 0; jn < 13; ++jn) {
                const float p = __expf((s[jn][j] - m) * scale);
                s[jn][j] = p;
                sum += p;
            }
            sum += __shfl_xor(sum, 1, 64);
            sum += __shfl_xor(sum, 2, 64);
            sum += __shfl_xor(sum, 4, 64);
            sum += __shfl_xor(sum, 8, 64);
            inv[j] = 1.0f / sum;
        }
#pragma unroll
        for (int jn = 0; jn < 13; ++jn)
#pragma unroll
            for (int j = 0; j < 4; ++j)
                pw[(lg * 4 + j) * 232 + jn * 16 + lr] = f2bf(s[jn][j]);

        f32x4 o0 = (f32x4)0.f, o1 = (f32x4)0.f;
#pragma unroll
        for (int kt = 0; kt < 7; ++kt) {
            const bf16x8 pf = *(const bf16x8*)(pw + lr * 232 + kt * 32 + lg * 8);
            const bf16x8 v0 = *(const bf16x8*)(Vt + lr * 232 + kt * 32 + lg * 8);
            const bf16x8 v1 = *(const bf16x8*)(Vt + (16 + lr) * 232 + kt * 32 + lg * 8);
            o0 = __builtin_amdgcn_mfma_f32_16x16x32_bf16(pf, v0, o0, 0, 0, 0);
            o1 = __builtin_amdgcn_mfma_f32_16x16x32_bf16(pf, v1, o1, 0, 0, 0);
        }
#pragma unroll
        for (int j = 0; j < 4; ++j) {
            const int r = qt * 16 + lg * 4 + j;
            if (r < 196) {
                const size_t o = ((size_t)r * 256 + b) * 128 + h * 32;
                ob[o + lr]      = f2bf(o0[j] * inv[j]);
                ob[o + 16 + lr] = f2bf(o1[j] * inv[j]);
            }
        }
    }
}

// ---------------------------------------------------------------------------
// Fused attention (f32, decoder cross path; verified r1).
// ---------------------------------------------------------------------------
__global__ __launch_bounds__(256) void k_attn(
    const float* __restrict__ qp, int qstride,
    const float* __restrict__ kvp, int kvstride, int koff, int voff,
    float* __restrict__ op, ushort* __restrict__ ob,
    int Lq, int Lk, float scale)
{
    __shared__ float Kl[196 * 36];
    __shared__ float Vl[196 * 32];
    __shared__ float pbuf[4][256];
    const int bh = blockIdx.x;
    const int b = bh >> 2;
    const int h = bh & 3;
    const int t = threadIdx.x;
    const int w = t >> 6;
    const int l = t & 63;

    for (int idx = t; idx < Lk * 8; idx += 256) {
        const int j = idx >> 3;
        const int kq = idx & 7;
        const size_t row = ((size_t)j * 256 + b) * kvstride + h * 32 + kq * 4;
        *(float4*)(&Kl[j * 36 + kq * 4]) = *(const float4*)(kvp + row + koff);
        *(float4*)(&Vl[j * 32 + kq * 4]) = *(const float4*)(kvp + row + voff);
    }
    if ((Lk & 1) && t < 8) *(float4*)(&Vl[Lk * 32 + t * 4]) = make_float4(0.f, 0.f, 0.f, 0.f);
    __syncthreads();

    const int Lh = (Lk + 1) >> 1;
    const int half = l >> 5;
    const int kk = l & 31;
    const int jb = half * Lh;

    for (int jq = w; jq < Lq; jq += 4) {
        const float* qrow = qp + ((size_t)jq * 256 + b) * qstride + h * 32;
        float4 q4[8];
#pragma unroll
        for (int kq = 0; kq < 8; ++kq) q4[kq] = *(const float4*)(qrow + kq * 4);

        float s[4];
#pragma unroll
        for (int r = 0; r < 4; ++r) {
            const int j = l + (r << 6);
            float acc = -3.0e38f;
            if (j < Lk) {
                acc = 0.f;
#pragma unroll
                for (int kq = 0; kq < 8; ++kq) {
                    const float4 kv = *(const float4*)(&Kl[j * 36 + kq * 4]);
                    acc += q4[kq].x * kv.x + q4[kq].y * kv.y +
                           q4[kq].z * kv.z + q4[kq].w * kv.w;
                }
                acc *= scale;
            }
            s[r] = acc;
        }
        float m = fmaxf(fmaxf(s[0], s[1]), fmaxf(s[2], s[3]));
        m = wred_max(m);
        float sum = 0.f;
#pragma unroll
        for (int r = 0; r < 4; ++r) {
            const int j = l + (r << 6);
            float p = __expf(s[r] - m);
            if (j >= Lk) p = 0.f;
            pbuf[w][j] = p;
            sum += p;
        }
        sum = wred_sum(sum);
        const float inv = 1.0f / sum;
        __threadfence_block();

        float o = 0.f;
        for (int jj = 0; jj < Lh; ++jj) {
            const float pv = pbuf[w][jb + jj];
            const float vv = Vl[(jb + jj) * 32 + kk];
            o += pv * vv;
        }
        o += __shfl_xor(o, 32, 64);
        o *= inv;
        if (l < 32) {
            const size_t oi = ((size_t)jq * 256 + b) * 128 + h * 32 + l;
            if (op) op[oi] = o;
            if (ob) ob[oi] = f2bf(o);
        }
        __threadfence_block();
    }
}

// ---------------------------------------------------------------------------
// Fused decoder part 1 v3 (512 threads, one block per batch b).
// All weight-consuming phases use K-split partial sums and/or
// load-once-FMA-many (k-outer, multi-row accumulators) to break the
// serial load->FMA chains that made v1/v2 latency-bound (r6/r8: 120us).
// ---------------------------------------------------------------------------
__global__ __launch_bounds__(512) void k_dec1(
    const float* __restrict__ sk,
    const float* __restrict__ W1, const float* __restrict__ b1,
    const float* __restrict__ W2, const float* __restrict__ b2,
    const float* __restrict__ W3, const float* __restrict__ b3,
    const float* __restrict__ ang, const float* __restrict__ px,
    const float* __restrict__ py,
    const float* __restrict__ actW, const float* __restrict__ actb,
    const float* __restrict__ saW, const float* __restrict__ sab,
    const float* __restrict__ saoW, const float* __restrict__ saob,
    const float* __restrict__ ln1s, const float* __restrict__ ln1b,
    const float* __restrict__ caW, const float* __restrict__ cab,
    float* __restrict__ TGo, float* __restrict__ DQ)
{
    __shared__ float tg[15][128];
    __shared__ float qkv[15][388];   // +4 pad
    __shared__ float ao[15][128];
    __shared__ float xr[256], h1[256], h2[256];
    __shared__ float s3[100];
    __shared__ float hp[4][256];     // K-split partial sums (reused per phase)
    __shared__ float pbv[4][16];
    const int b = blockIdx.x, t = threadIdx.x;
    const int w = t >> 6, l = t & 63;

    if (t < 256) xr[t] = (t < 200) ? sk[(size_t)b * 200 + t] : 0.f;
    __syncthreads();
    // h1: 256 outputs, K=200 split 2x100 across 512 threads
    {
        const int c = t & 255, g = t >> 8;
        const int k0 = g * 100;
        float a = 0.f;
#pragma unroll 10
        for (int k = k0; k < k0 + 100; ++k) a += xr[k] * W1[k * 256 + c];
        hp[g][c] = a;
    }
    __syncthreads();
    if (t < 256) h1[t] = fmaxf(hp[0][t] + hp[1][t] + b1[t], 0.f);
    __syncthreads();
    // h2: 256 outputs, K=256 split 2x128
    {
        const int c = t & 255, g = t >> 8;
        const int k0 = g * 128;
        float a = 0.f;
#pragma unroll 8
        for (int k = k0; k < k0 + 128; ++k) a += h1[k] * W2[k * 256 + c];
        hp[g][c] = a;
    }
    __syncthreads();
    if (t < 256) h2[t] = fmaxf(hp[0][t] + hp[1][t] + b2[t], 0.f);
    __syncthreads();
    // s3: 100 outputs, K=256 split 4x64 (400 threads)
    if (t < 400) {
        const int c = t % 100, g = t / 100;
        const int k0 = g * 64;
        float a = 0.f;
#pragma unroll 8
        for (int k = k0; k < k0 + 64; ++k) a += h2[k] * W3[k * 100 + c];
        hp[g][c] = a;
    }
    __syncthreads();
    if (t < 100) s3[t] = hp[0][t] + hp[1][t] + hp[2][t] + hp[3][t] + b3[t];
    __syncthreads();
    // tgt base: 128 outputs, K=100 split 4x25
    {
        const int c = t & 127, g = t >> 7;
        const int k0 = g * 25;
        float a = 0.f;
#pragma unroll 5
        for (int k = k0; k < k0 + 25; ++k) a += s3[k] * actW[(18 + k) * 128 + c];
        hp[g][c] = a;
    }
    __syncthreads();
    if (t < 128) {
        const float base = actb[t] + hp[0][t] + hp[1][t] + hp[2][t] + hp[3][t] +
                           ang[b] * actW[15 * 128 + t] + px[b] * actW[16 * 128 + t] +
                           py[b] * actW[17 * 128 + t];
#pragma unroll
        for (int i = 0; i < 15; ++i) tg[i][t] = base + actW[i * 128 + t];
    }
    __syncthreads();

    // self QKV: 384 lanes, 15 rows in regs (1 load : 15 FMA)
    if (t < 384) {
        float acc[15];
#pragma unroll
        for (int r = 0; r < 15; ++r) acc[r] = 0.f;
#pragma unroll 4
        for (int k = 0; k < 128; ++k) {
            const float wv = saW[(size_t)k * 384 + t];
#pragma unroll
            for (int r = 0; r < 15; ++r) acc[r] += tg[r][k] * wv;
        }
        const float bb = sab[t];
#pragma unroll
        for (int r = 0; r < 15; ++r) qkv[r][t] = acc[r] + bb;
    }
    __syncthreads();

    // self-attn: waves 0..3 = heads
    const float rs = 0.17677669529663687f;
    if (w < 4) {
        for (int qi = 0; qi < 15; ++qi) {
            float s = -3.0e38f;
            if (l < 15) {
                s = 0.f;
#pragma unroll
                for (int d = 0; d < 32; ++d)
                    s += qkv[qi][w * 32 + d] * qkv[l][128 + w * 32 + d];
                s *= rs;
            }
            const float m = wred_max(s);
            const float pv = (l < 15) ? __expf(s - m) : 0.f;
            const float sum = wred_sum(pv);
            if (l < 15) pbv[w][l] = pv;
            if (l < 32) {
                float o = 0.f;
#pragma unroll
                for (int j = 0; j < 15; ++j) o += pbv[w][j] * qkv[j][256 + w * 32 + l];
                ao[qi][w * 32 + l] = o / sum;
            }
        }
    }
    __syncthreads();

    // SA out-proj + residual: k-outer, 4 rows per thread (1 load : 4 FMA)
    {
        const int c = t & 127, g = t >> 7;
        const int r3 = (g + 12 < 15) ? g + 12 : 0;
        float a0 = 0.f, a1 = 0.f, a2 = 0.f, a3 = 0.f;
#pragma unroll 4
        for (int k = 0; k < 128; ++k) {
            const float wv = saoW[(size_t)k * 128 + c];
            a0 += ao[g][k] * wv;
            a1 += ao[g + 4][k] * wv;
            a2 += ao[g + 8][k] * wv;
            a3 += ao[r3][k] * wv;
        }
        const float bb = saob[c];
        qkv[g][c]     = a0 + bb + tg[g][c];
        qkv[g + 4][c] = a1 + bb + tg[g + 4][c];
        qkv[g + 8][c] = a2 + bb + tg[g + 8][c];
        if (g + 12 < 15) qkv[g + 12][c] = a3 + bb + tg[g + 12][c];
    }
    __syncthreads();
    // LN1 (8 waves) -> tg + TGo
    for (int r = w; r < 15; r += 8) {
        const float x0 = qkv[r][l], x1 = qkv[r][l + 64];
        const float sm = wred_sum(x0 + x1);
        const float sq = wred_sum(x0 * x0 + x1 * x1);
        const float mean = sm * 0.0078125f;
        const float rstd = rsqrtf(sq * 0.0078125f - mean * mean + 1e-5f);
        const float y0 = (x0 - mean) * rstd * ln1s[l] + ln1b[l];
        const float y1 = (x1 - mean) * rstd * ln1s[l + 64] + ln1b[l + 64];
        tg[r][l] = y0; tg[r][l + 64] = y1;
        float* g2 = TGo + ((size_t)r * 256 + b) * 128;
        g2[l] = y0; g2[l + 64] = y1;
    }
    __syncthreads();

    // cross Q: k-outer, 4 rows per thread
    {
        const int c = t & 127, g = t >> 7;
        const int r3 = (g + 12 < 15) ? g + 12 : 0;
        float a0 = 0.f, a1 = 0.f, a2 = 0.f, a3 = 0.f;
#pragma unroll 4
        for (int k = 0; k < 128; ++k) {
            const float wv = caW[(size_t)k * 384 + c];
            a0 += tg[g][k] * wv;
            a1 += tg[g + 4][k] * wv;
            a2 += tg[g + 8][k] * wv;
            a3 += tg[r3][k] * wv;
        }
        const float bb = cab[c];
        DQ[((size_t)g * 256 + b) * 128 + c]       = a0 + bb;
        DQ[((size_t)(g + 4) * 256 + b) * 128 + c] = a1 + bb;
        DQ[((size_t)(g + 8) * 256 + b) * 128 + c] = a2 + bb;
        if (g + 12 < 15) DQ[((size_t)(g + 12) * 256 + b) * 128 + c] = a3 + bb;
    }
}

// ---------------------------------------------------------------------------
// Fused decoder part 2 v3 (512 threads, one block per batch b).
// Same k-outer / multi-row-accumulator restructuring as k_dec1.
// ---------------------------------------------------------------------------
__global__ __launch_bounds__(512) void k_dec2(
    const float* __restrict__ TGo, const float* __restrict__ AT,
    const float* __restrict__ caoW, const float* __restrict__ caob,
    const float* __restrict__ ln2s, const float* __restrict__ ln2b,
    const float* __restrict__ ff1W, const float* __restrict__ ff1b,
    const float* __restrict__ ff2W, const float* __restrict__ ff2b,
    const float* __restrict__ ln3s, const float* __restrict__ ln3b,
    const float* __restrict__ ns, const float* __restrict__ nb,
    const float* __restrict__ l1W, const float* __restrict__ l1b,
    const float* __restrict__ l2w, const float* __restrict__ l2b,
    float* __restrict__ qout)
{
    __shared__ float tg[15][128], ao[15][128], o2[15][128];
    __shared__ float ff[15][64];
    const int b = blockIdx.x, t = threadIdx.x;
    const int w = t >> 6, l = t & 63;

    for (int idx = t; idx < 1920; idx += 512) {
        const int r = idx >> 7, c = idx & 127;
        tg[r][c] = TGo[((size_t)r * 256 + b) * 128 + c];
        ao[r][c] = AT[((size_t)r * 256 + b) * 128 + c];
    }
    __syncthreads();

    // CA out-proj + residual: k-outer, 4 rows per thread
    {
        const int c = t & 127, g = t >> 7;
        const int r3 = (g + 12 < 15) ? g + 12 : 0;
        float a0 = 0.f, a1 = 0.f, a2 = 0.f, a3 = 0.f;
#pragma unroll 4
        for (int k = 0; k < 128; ++k) {
            const float wv = caoW[(size_t)k * 128 + c];
            a0 += ao[g][k] * wv;
            a1 += ao[g + 4][k] * wv;
            a2 += ao[g + 8][k] * wv;
            a3 += ao[r3][k] * wv;
        }
        const float bb = caob[c];
        o2[g][c]     = a0 + bb + tg[g][c];
        o2[g + 4][c] = a1 + bb + tg[g + 4][c];
        o2[g + 8][c] = a2 + bb + tg[g + 8][c];
        if (g + 12 < 15) o2[g + 12][c] = a3 + bb + tg[g + 12][c];
    }
    __syncthreads();
    // LN2 (8 waves) -> tg
    for (int r = w; r < 15; r += 8) {
        const float x0 = o2[r][l], x1 = o2[r][l + 64];
        const float sm = wred_sum(x0 + x1);
        const float sq = wred_sum(x0 * x0 + x1 * x1);
        const float mean = sm * 0.0078125f;
        const float rstd = rsqrtf(sq * 0.0078125f - mean * mean + 1e-5f);
        tg[r][l]      = (x0 - mean) * rstd * ln2s[l] + ln2b[l];
        tg[r][l + 64] = (x1 - mean) * rstd * ln2s[l + 64] + ln2b[l + 64];
    }
    __syncthreads();
    // FF1 (relu): k-outer, 8 col-groups x 2 rows
    {
        const int n = t & 63, g = t >> 6;
        const int r1 = (g + 8 < 15) ? g + 8 : 0;
        float a0 = 0.f, a1 = 0.f;
#pragma unroll 4
        for (int k = 0; k < 128; ++k) {
            const float wv = ff1W[(size_t)k * 64 + n];
            a0 += tg[g][k] * wv;
            a1 += tg[r1][k] * wv;
        }
        const float bb = ff1b[n];
        ff[g][n] = fmaxf(a0 + bb, 0.f);
        if (g + 8 < 15) ff[g + 8][n] = fmaxf(a1 + bb, 0.f);
    }
    __syncthreads();
    // FF2 + residual: k-outer (K=64), 4 rows per thread
    {
        const int c = t & 127, g = t >> 7;
        const int r3 = (g + 12 < 15) ? g + 12 : 0;
        float a0 = 0.f, a1 = 0.f, a2 = 0.f, a3 = 0.f;
#pragma unroll 4
        for (int k = 0; k < 64; ++k) {
            const float wv = ff2W[(size_t)k * 128 + c];
            a0 += ff[g][k] * wv;
            a1 += ff[g + 4][k] * wv;
            a2 += ff[g + 8][k] * wv;
            a3 += ff[r3][k] * wv;
        }
        const float bb = ff2b[c];
        o2[g][c]     = a0 + bb + tg[g][c];
        o2[g + 4][c] = a1 + bb + tg[g + 4][c];
        o2[g + 8][c] = a2 + bb + tg[g + 8][c];
        if (g + 12 < 15) o2[g + 12][c] = a3 + bb + tg[g + 12][c];
    }
    __syncthreads();
    // LN3 then dec_norm (8 waves) -> tg
    for (int r = w; r < 15; r += 8) {
        const float x0 = o2[r][l], x1 = o2[r][l + 64];
        const float sm = wred_sum(x0 + x1);
        const float sq = wred_sum(x0 * x0 + x1 * x1);
        const float mean = sm * 0.0078125f;
        const float rstd = rsqrtf(sq * 0.0078125f - mean * mean + 1e-5f);
        const float y0 = (x0 - mean) * rstd * ln3s[l] + ln3b[l];
        const float y1 = (x1 - mean) * rstd * ln3s[l + 64] + ln3b[l + 64];
        const float sm2 = wred_sum(y0 + y1);
        const float sq2 = wred_sum(y0 * y0 + y1 * y1);
        const float mean2 = sm2 * 0.0078125f;
        const float rstd2 = rsqrtf(sq2 * 0.0078125f - mean2 * mean2 + 1e-5f);
        tg[r][l]      = (y0 - mean2) * rstd2 * ns[l] + nb[l];
        tg[r][l + 64] = (y1 - mean2) * rstd2 * ns[l + 64] + nb[l + 64];
    }
    __syncthreads();
    // l1 (relu): k-outer, 4 rows per thread
    {
        const int c = t & 127, g = t >> 7;
        const int r3 = (g + 12 < 15) ? g + 12 : 0;
        float a0 = 0.f, a1 = 0.f, a2 = 0.f, a3 = 0.f;
#pragma unroll 4
        for (int k = 0; k < 128; ++k) {
            const float wv = l1W[(size_t)k * 128 + c];
            a0 += tg[g][k] * wv;
            a1 += tg[g + 4][k] * wv;
            a2 += tg[g + 8][k] * wv;
            a3 += tg[r3][k] * wv;
        }
        const float bb = l1b[c];
        o2[g][c]     = fmaxf(a0 + bb, 0.f);
        o2[g + 4][c] = fmaxf(a1 + bb, 0.f);
        o2[g + 8][c] = fmaxf(a2 + bb, 0.f);
        if (g + 12 < 15) o2[g + 12][c] = fmaxf(a3 + bb, 0.f);
    }
    __syncthreads();
    // head dot (8 waves)
    for (int r = w; r < 15; r += 8) {
        const float d = wred_sum(o2[r][l] * l2w[l] + o2[r][l + 64] * l2w[l + 64]);
        if (l == 0) qout[b * 15 + r] = d + l2b[0];
    }
}

// ---------------------------------------------------------------------------
extern "C" void kernel_launch(void* const* d_in, const int* in_sizes, int n_in,
                              void* d_out, int out_size, void* d_ws, size_t ws_size,
                              hipStream_t stream)
{
    (void)in_sizes; (void)n_in; (void)out_size; (void)ws_size;
    const float* image      = (const float*)d_in[0];
    const float* angle      = (const float*)d_in[1];
    const float* pos_x      = (const float*)d_in[2];
    const float* pos_y      = (const float*)d_in[3];
    const float* sk         = (const float*)d_in[4];
    const float* patch_W    = (const float*)d_in[5];
    const float* patch_b    = (const float*)d_in[6];
    const float* pos_emb    = (const float*)d_in[7];
    const float* enc_qkv_W  = (const float*)d_in[8];
    const float* enc_qkv_b  = (const float*)d_in[9];
    const float* enc_out_W  = (const float*)d_in[10];
    const float* enc_out_b  = (const float*)d_in[11];
    const float* enc_ln1_s  = (const float*)d_in[12];
    const float* enc_ln1_b  = (const float*)d_in[13];
    const float* enc_ff1_W  = (const float*)d_in[14];
    const float* enc_ff1_b  = (const float*)d_in[15];
    const float* enc_ff2_W  = (const float*)d_in[16];
    const float* enc_ff2_b  = (const float*)d_in[17];
    const float* enc_ln2_s  = (const float*)d_in[18];
    const float* enc_ln2_b  = (const float*)d_in[19];
    const float* dec_sa_qkv_W = (const float*)d_in[20];
    const float* dec_sa_qkv_b = (const float*)d_in[21];
    const float* dec_sa_out_W = (const float*)d_in[22];
    const float* dec_sa_out_b = (const float*)d_in[23];
    const float* dec_ca_qkv_W = (const float*)d_in[24];
    const float* dec_ca_qkv_b = (const float*)d_in[25];
    const float* dec_ca_out_W = (const float*)d_in[26];
    const float* dec_ca_out_b = (const float*)d_in[27];
    const float* dec_ln1_s  = (const float*)d_in[28];
    const float* dec_ln1_b  = (const float*)d_in[29];
    const float* dec_ln2_s  = (const float*)d_in[30];
    const float* dec_ln2_b  = (const float*)d_in[31];
    const float* dec_ln3_s  = (const float*)d_in[32];
    const float* dec_ln3_b  = (const float*)d_in[33];
    const float* dec_ff1_W  = (const float*)d_in[34];
    const float* dec_ff1_b  = (const float*)d_in[35];
    const float* dec_ff2_W  = (const float*)d_in[36];
    const float* dec_ff2_b  = (const float*)d_in[37];
    const float* dec_norm_s = (const float*)d_in[38];
    const float* dec_norm_b = (const float*)d_in[39];
    const float* sk1_W = (const float*)d_in[40];
    const float* sk1_b = (const float*)d_in[41];
    const float* sk2_W = (const float*)d_in[42];
    const float* sk2_b = (const float*)d_in[43];
    const float* sk3_W = (const float*)d_in[44];
    const float* sk3_b = (const float*)d_in[45];
    const float* act_W = (const float*)d_in[46];
    const float* act_b = (const float*)d_in[47];
    const float* l1_W  = (const float*)d_in[48];
    const float* l1_b  = (const float*)d_in[49];
    const float* l2_W  = (const float*)d_in[50];
    const float* l2_b  = (const float*)d_in[51];

    // Workspace (float offsets)
    float* ws = (float*)d_ws;
    float* S0   = ws;               // src f32 residual stream  [6,422,528]
    float* QKVr = ws + 6422528;     // big overlay region       [19,267,584]
    float* T0   = ws + 25690112;    // decoder cross-attn out   [6,422,528]
    float* T1   = ws + 32112640;    // M0b bf16 home            [6,422,528]
    float* F1   = ws + 38535168;    // F1b bf16                 [3,211,264]
    float* M0r  = ws + 41746432;    // srcb/T0b | lnb bf16      [6,422,528]
    float* S1s  = ws + 48168960;
    float* TG   = S1s + 156672;     // tgt f32 15*256*128
    ushort* WTS = (ushort*)(ws + 48817152);

    // Overlays
    ushort* QKVb = (ushort*)QKVr;            // enc QKV bf16 [50176][384]
    float*  KV   = QKVr;                     // cross K/V f32 [50176][256]
    float* DQ   = QKVr + 14319616;           // dec cross Q f32
    float* DT0  = T0;
    ushort* srcb = (ushort*)M0r;
    ushort* T0b  = (ushort*)M0r;             // disjoint lifetime with srcb
    ushort* lnb  = (ushort*)(M0r + 3211264);
    ushort* F1b  = (ushort*)F1;
    ushort* M0b  = (ushort*)T1;
    ushort* wt_patch = WTS;
    ushort* wt_qkv   = WTS + 98304;
    ushort* wt_out   = WTS + 147456;
    ushort* wt_ff1   = WTS + 163840;
    ushort* wt_ff2   = WTS + 172032;
    ushort* wt_ckv   = WTS + 180224;

    const float rs = 0.17677669529663687f;  // 1/sqrt(32)

    // ---- prep ----
    k_wconv<<<dim3(832), 256, 0, stream>>>(patch_W, enc_qkv_W, enc_out_W,
                                           enc_ff1_W, enc_ff2_W, dec_ca_qkv_W, WTS);
    k_dec1<<<dim3(256), 512, 0, stream>>>(
        sk, sk1_W, sk1_b, sk2_W, sk2_b, sk3_W, sk3_b,
        angle, pos_x, pos_y, act_W, act_b,
        dec_sa_qkv_W, dec_sa_qkv_b, dec_sa_out_W, dec_sa_out_b,
        dec_ln1_s, dec_ln1_b, dec_ca_qkv_W, dec_ca_qkv_b, TG, DQ);

    // ---- encoder ----
    k_pgemm<<<dim3(784), 256, 0, stream>>>(
        image, wt_patch, patch_b, pos_emb, S0, srcb);
    k_gemm_bf16<64, 128><<<dim3(784, 3), 256, 0, stream>>>(
        srcb, 128, wt_qkv, 128, enc_qkv_b, nullptr, QKVb, 384, nullptr, 0);
    k_attn_mfma<<<dim3(1024), 256, 0, stream>>>(QKVb, T0b, rs);
    k_gemm_ln<<<dim3(784), 256, 0, stream>>>(                 // out-proj + LN1
        T0b, 128, wt_out, 128, enc_out_b, S0, enc_ln1_s, enc_ln1_b, S0, lnb);
    k_gemm_bf16<64, 64><<<dim3(784, 1), 256, 0, stream>>>(    // FF1 + relu
        lnb, 128, wt_ff1, 128, enc_ff1_b, nullptr, F1b, 64, nullptr, 1);
    k_gemm_ln<<<dim3(784), 256, 0, stream>>>(                 // FF2 + LN2
        F1b, 64, wt_ff2, 64, enc_ff2_b, S0, enc_ln2_s, enc_ln2_b, nullptr, M0b);
    k_gemm_bf16<64, 128><<<dim3(784, 2), 256, 0, stream>>>(   // cross K/V
        M0b, 128, wt_ckv, 128, dec_ca_qkv_b + 128, KV, nullptr, 256, nullptr, 0);

    // ---- decoder cross-attn + tail ----
    k_attn<<<dim3(1024), 256, 0, stream>>>(DQ, 128, KV, 256, 0, 128,
                                           DT0, nullptr, 15, 196, rs);
    k_dec2<<<dim3(256), 512, 0, stream>>>(
        TG, DT0, dec_ca_out_W, dec_ca_out_b, dec_ln2_s, dec_ln2_b,
        dec_ff1_W, dec_ff1_b, dec_ff2_W, dec_ff2_b,
        dec_ln3_s, dec_ln3_b, dec_norm_s, dec_norm_b,
        l1_W, l1_b, l2_W, l2_b, (float*)d_out);
}

// Round 10
// 352.945 us; speedup vs baseline: 1.3530x; 1.1109x over previous
//
#include <hip/hip_runtime.h>
#include <math.h>

#define BSZ 256
#define DIM 128
#define NHD 4
#define NPATCH 196
#define NACT 15

typedef float f32x4 __attribute__((ext_vector_type(4)));
typedef __bf16 bf16x8 __attribute__((ext_vector_type(8)));
typedef short short8 __attribute__((ext_vector_type(8)));

__device__ __forceinline__ float wred_sum(float v) {
#pragma unroll
    for (int m = 1; m < 64; m <<= 1) v += __shfl_xor(v, m, 64);
    return v;
}
__device__ __forceinline__ float wred_max(float v) {
#pragma unroll
    for (int m = 1; m < 64; m <<= 1) v = fmaxf(v, __shfl_xor(v, m, 64));
    return v;
}
__device__ __forceinline__ ushort f2bf(float f) {  // RNE bf16
    unsigned u = __float_as_uint(f);
    return (ushort)((u + 0x7fffu + ((u >> 16) & 1u)) >> 16);
}

// ---------------------------------------------------------------------------
// Weight convert+transpose to bf16 [N][K] (patch K-permuted), packed.
// ---------------------------------------------------------------------------
__global__ __launch_bounds__(256) void k_wconv(
    const float* __restrict__ pW, const float* __restrict__ qkvW,
    const float* __restrict__ outW, const float* __restrict__ ff1W,
    const float* __restrict__ ff2W, const float* __restrict__ ckvW,
    ushort* __restrict__ o)
{
    int i = blockIdx.x * 256 + threadIdx.x;
    if (i < 98304) {
        int n = i / 768, kp = i % 768;
        int c = kp >> 8, q = kp & 255;
        o[i] = f2bf(pW[(q * 3 + c) * 128 + n]); return;
    }
    i -= 98304;
    if (i < 49152) { int n = i >> 7, k = i & 127; o[98304 + i] = f2bf(qkvW[k * 384 + n]); return; }
    i -= 49152;
    if (i < 16384) { int n = i >> 7, k = i & 127; o[147456 + i] = f2bf(outW[k * 128 + n]); return; }
    i -= 16384;
    if (i < 8192)  { int n = i >> 7, k = i & 127; o[163840 + i] = f2bf(ff1W[k * 64 + n]); return; }
    i -= 8192;
    if (i < 8192)  { int n = i >> 6, k = i & 63;  o[172032 + i] = f2bf(ff2W[k * 128 + n]); return; }
    i -= 8192;
    if (i < 32768) { int n = i >> 7, k = i & 127; o[180224 + i] = f2bf(ckvW[k * 384 + 128 + n]); return; }
}

// ---------------------------------------------------------------------------
// Fused patchify + patch-embed MFMA GEMM v2: double-buffered LDS + register
// prefetch one tile ahead; ONE barrier per k-step. Hazard analysis: buffer X
// is written only after the barrier that follows all reads of X (ping-pong),
// so the second barrier of the classic loop is unnecessary.
// ---------------------------------------------------------------------------
__global__ __launch_bounds__(256) void k_pgemm(
    const float* __restrict__ img, const ushort* __restrict__ Wt,
    const float* __restrict__ bias, const float* __restrict__ pe,
    float* __restrict__ C, ushort* __restrict__ Cb)
{
    __shared__ ushort As[2][64 * 64];
    __shared__ ushort Ws[2][128 * 64];
    const int t = threadIdx.x;
    const int w = t >> 6, l = t & 63;
    const int pb = blockIdx.x;
    const int p = pb >> 2, bq = pb & 3;
    const int hp = p / 14, wp = p % 14;
    const int r0 = p * 256 + bq * 64;
    const int wm = w >> 1, wn = w & 1;
    const int lrow = l & 15, lk = l >> 4;
    const int arow = t >> 2;
    const int b_img = bq * 64 + arow;
    const float* gimg = img + (size_t)b_img * 150528 + hp * 3584 + wp * 16;

    f32x4 acc[2][4];
#pragma unroll
    for (int m = 0; m < 2; ++m)
#pragma unroll
        for (int n = 0; n < 4; ++n) acc[m][n] = (f32x4)0.f;

    float4 va[4];    // prefetched image chunk (tile k+1)
    short8 wr[4];    // prefetched weight chunk

    auto loadT = [&](int kc) {
        const int c = kc >> 8, p1q = (kc >> 6) & 3;
        const float* gc = gimg + c * 50176 + p1q * 896;
#pragma unroll
        for (int i = 0; i < 4; ++i)
            va[i] = *(const float4*)(gc + i * 224 + (t & 3) * 4);
#pragma unroll
        for (int j = 0; j < 4; ++j) {
            const int i2 = t + 256 * j;
            const int row = i2 >> 3, ch = i2 & 7;
            wr[j] = *(const short8*)(Wt + (size_t)row * 768 + kc + ch * 8);
        }
    };
    auto storeT = [&](int buf) {
#pragma unroll
        for (int i = 0; i < 4; ++i) {
            ushort4 o4;
            o4.x = f2bf(va[i].x); o4.y = f2bf(va[i].y);
            o4.z = f2bf(va[i].z); o4.w = f2bf(va[i].w);
            const int kq = (t & 3) + 4 * i;
            const int bo = (kq * 8) ^ ((arow & 7) << 4);
            *(ushort4*)((char*)As[buf] + arow * 128 + bo) = o4;
        }
#pragma unroll
        for (int j = 0; j < 4; ++j) {
            const int i2 = t + 256 * j;
            const int row = i2 >> 3, ch = i2 & 7;
            const int sw = (ch * 16) ^ ((row & 7) << 4);
            *(short8*)((char*)Ws[buf] + row * 128 + sw) = wr[j];
        }
    };
    auto mfmaT = [&](int buf) {
#pragma unroll
        for (int ks = 0; ks < 2; ++ks) {
            bf16x8 af[2], bfr[4];
#pragma unroll
            for (int m = 0; m < 2; ++m) {
                const int row = wm * 32 + m * 16 + lrow;
                const int col = (ks * 64 + lk * 16) ^ ((row & 7) << 4);
                af[m] = *(const bf16x8*)((const char*)As[buf] + row * 128 + col);
            }
#pragma unroll
            for (int n = 0; n < 4; ++n) {
                const int row = wn * 64 + n * 16 + lrow;
                const int col = (ks * 64 + lk * 16) ^ ((row & 7) << 4);
                bfr[n] = *(const bf16x8*)((const char*)Ws[buf] + row * 128 + col);
            }
#pragma unroll
            for (int m = 0; m < 2; ++m)
#pragma unroll
                for (int n = 0; n < 4; ++n)
                    acc[m][n] = __builtin_amdgcn_mfma_f32_16x16x32_bf16(
                        af[m], bfr[n], acc[m][n], 0, 0, 0);
        }
    };

    loadT(0);
    for (int it = 0; it < 12; it += 2) {
        storeT(0);                              // tile it -> buf0
        if (it + 1 < 12) loadT((it + 1) * 64);  // prefetch tile it+1
        __syncthreads();
        mfmaT(0);
        storeT(1);                              // tile it+1 -> buf1
        if (it + 2 < 12) loadT((it + 2) * 64);  // prefetch tile it+2
        __syncthreads();
        mfmaT(1);
    }

    const int crow0 = (l >> 4) * 4;
    const int ccol = l & 15;
#pragma unroll
    for (int m = 0; m < 2; ++m) {
        const int growb = r0 + wm * 32 + m * 16 + crow0;
#pragma unroll
        for (int n = 0; n < 4; ++n) {
            const int gcol = wn * 64 + n * 16 + ccol;
            const float bv = bias[gcol] + pe[p * 128 + gcol];
#pragma unroll
            for (int j = 0; j < 4; ++j) {
                const int grow = growb + j;
                const float v = acc[m][n][j] + bv;
                C[(size_t)grow * 128 + gcol] = v;
                Cb[(size_t)grow * 128 + gcol] = f2bf(v);
            }
        }
    }
}

// ---------------------------------------------------------------------------
// bf16 MFMA GEMM, BM x BN tile (verified).
// ---------------------------------------------------------------------------
template <int BM, int BN>
__global__ __launch_bounds__(256) void k_gemm_bf16(
    const ushort* __restrict__ A, int lda,
    const ushort* __restrict__ Wt, int K,
    const float* __restrict__ bias,
    float* __restrict__ C, ushort* __restrict__ Cb, int ldc,
    const float* __restrict__ pe, int relu)
{
    constexpr int NWN = BN / 64;
    constexpr int NWM = 4 / NWN;
    constexpr int WTM = BM / NWM;
    constexpr int MF = WTM / 16;
    __shared__ ushort As[BM * 64];
    __shared__ ushort Ws[BN * 64];
    const int t = threadIdx.x;
    const int w = t >> 6, l = t & 63;
    const int r0 = blockIdx.x * BM;
    const int n0 = blockIdx.y * BN;
    const int wm = w / NWN, wn = w % NWN;
    const int lrow = l & 15, lk = l >> 4;

    f32x4 acc[MF][4];
#pragma unroll
    for (int m = 0; m < MF; ++m)
#pragma unroll
        for (int n = 0; n < 4; ++n) acc[m][n] = (f32x4)0.f;

    for (int kc = 0; kc < K; kc += 64) {
        __syncthreads();
#pragma unroll
        for (int i = t; i < BM * 8; i += 256) {
            const int row = i >> 3, ch = i & 7;
            const int sw = (ch * 16) ^ ((row & 7) << 4);
            *(short8*)((char*)As + row * 128 + sw) =
                *(const short8*)(A + (size_t)(r0 + row) * lda + kc + ch * 8);
        }
#pragma unroll
        for (int i = t; i < BN * 8; i += 256) {
            const int row = i >> 3, ch = i & 7;
            const int sw = (ch * 16) ^ ((row & 7) << 4);
            *(short8*)((char*)Ws + row * 128 + sw) =
                *(const short8*)(Wt + (size_t)(n0 + row) * K + kc + ch * 8);
        }
        __syncthreads();
#pragma unroll
        for (int ks = 0; ks < 2; ++ks) {
            bf16x8 af[MF], bfr[4];
#pragma unroll
            for (int m = 0; m < MF; ++m) {
                const int row = wm * WTM + m * 16 + lrow;
                const int col = (ks * 64 + lk * 16) ^ ((row & 7) << 4);
                af[m] = *(const bf16x8*)((const char*)As + row * 128 + col);
            }
#pragma unroll
            for (int n = 0; n < 4; ++n) {
                const int row = wn * 64 + n * 16 + lrow;
                const int col = (ks * 64 + lk * 16) ^ ((row & 7) << 4);
                bfr[n] = *(const bf16x8*)((const char*)Ws + row * 128 + col);
            }
#pragma unroll
            for (int m = 0; m < MF; ++m)
#pragma unroll
                for (int n = 0; n < 4; ++n)
                    acc[m][n] = __builtin_amdgcn_mfma_f32_16x16x32_bf16(
                        af[m], bfr[n], acc[m][n], 0, 0, 0);
        }
    }

    const int crow0 = (l >> 4) * 4;
    const int ccol = l & 15;
#pragma unroll
    for (int m = 0; m < MF; ++m) {
        const int growb = r0 + wm * WTM + m * 16 + crow0;
#pragma unroll
        for (int n = 0; n < 4; ++n) {
            const int gcol = n0 + wn * 64 + n * 16 + ccol;
            const float bv = bias[gcol];
#pragma unroll
            for (int j = 0; j < 4; ++j) {
                const int grow = growb + j;
                float v = acc[m][n][j] + bv;
                if (pe) v += pe[(grow >> 8) * 128 + gcol];
                if (relu) v = fmaxf(v, 0.f);
                if (C)  C[(size_t)grow * ldc + gcol] = v;
                if (Cb) Cb[(size_t)grow * ldc + gcol] = f2bf(v);
            }
        }
    }
}

// ---------------------------------------------------------------------------
// bf16 MFMA GEMM 64x128 + residual + LayerNorm fused epilogue (verified r5).
// ---------------------------------------------------------------------------
__global__ __launch_bounds__(256) void k_gemm_ln(
    const ushort* __restrict__ A, int lda,
    const ushort* __restrict__ Wt, int K,
    const float* __restrict__ bias,
    const float* __restrict__ resid,
    const float* __restrict__ lns, const float* __restrict__ lnbi,
    float* __restrict__ Co, ushort* __restrict__ Cb)
{
    __shared__ ushort As[64 * 64];
    __shared__ ushort Ws[128 * 64];
    __shared__ float psum[64][2][2];
    const int t = threadIdx.x;
    const int w = t >> 6, l = t & 63;
    const int r0 = blockIdx.x * 64;
    const int wm = w >> 1, wn = w & 1;
    const int lrow = l & 15, lk = l >> 4;

    f32x4 acc[2][4];
#pragma unroll
    for (int m = 0; m < 2; ++m)
#pragma unroll
        for (int n = 0; n < 4; ++n) acc[m][n] = (f32x4)0.f;

    for (int kc = 0; kc < K; kc += 64) {
        __syncthreads();
#pragma unroll
        for (int i = t; i < 64 * 8; i += 256) {
            const int row = i >> 3, ch = i & 7;
            const int sw = (ch * 16) ^ ((row & 7) << 4);
            *(short8*)((char*)As + row * 128 + sw) =
                *(const short8*)(A + (size_t)(r0 + row) * lda + kc + ch * 8);
        }
#pragma unroll
        for (int i = t; i < 128 * 8; i += 256) {
            const int row = i >> 3, ch = i & 7;
            const int sw = (ch * 16) ^ ((row & 7) << 4);
            *(short8*)((char*)Ws + row * 128 + sw) =
                *(const short8*)(Wt + (size_t)row * K + kc + ch * 8);
        }
        __syncthreads();
#pragma unroll
        for (int ks = 0; ks < 2; ++ks) {
            bf16x8 af[2], bfr[4];
#pragma unroll
            for (int m = 0; m < 2; ++m) {
                const int row = wm * 32 + m * 16 + lrow;
                const int col = (ks * 64 + lk * 16) ^ ((row & 7) << 4);
                af[m] = *(const bf16x8*)((const char*)As + row * 128 + col);
            }
#pragma unroll
            for (int n = 0; n < 4; ++n) {
                const int row = wn * 64 + n * 16 + lrow;
                const int col = (ks * 64 + lk * 16) ^ ((row & 7) << 4);
                bfr[n] = *(const bf16x8*)((const char*)Ws + row * 128 + col);
            }
#pragma unroll
            for (int m = 0; m < 2; ++m)
#pragma unroll
                for (int n = 0; n < 4; ++n)
                    acc[m][n] = __builtin_amdgcn_mfma_f32_16x16x32_bf16(
                        af[m], bfr[n], acc[m][n], 0, 0, 0);
        }
    }

    const int crow0 = (l >> 4) * 4;
    const int ccol = l & 15;
#pragma unroll
    for (int m = 0; m < 2; ++m) {
        const int growb = r0 + wm * 32 + m * 16 + crow0;
#pragma unroll
        for (int n = 0; n < 4; ++n) {
            const int gcol = wn * 64 + n * 16 + ccol;
            const float bv = bias[gcol];
#pragma unroll
            for (int j = 0; j < 4; ++j) {
                float v = acc[m][n][j] + bv;
                if (resid) v += resid[(size_t)(growb + j) * 128 + gcol];
                acc[m][n][j] = v;
            }
        }
    }
#pragma unroll
    for (int m = 0; m < 2; ++m)
#pragma unroll
        for (int j = 0; j < 4; ++j) {
            float s_ = 0.f, q_ = 0.f;
#pragma unroll
            for (int n = 0; n < 4; ++n) {
                const float x = acc[m][n][j];
                s_ += x; q_ += x * x;
            }
#pragma unroll
            for (int mk = 1; mk < 16; mk <<= 1) {
                s_ += __shfl_xor(s_, mk, 64);
                q_ += __shfl_xor(q_, mk, 64);
            }
            if (ccol == 0) {
                const int r = wm * 32 + m * 16 + crow0 + j;
                psum[r][wn][0] = s_;
                psum[r][wn][1] = q_;
            }
        }
    __syncthreads();
    float mean_[2][4], rstd_[2][4];
#pragma unroll
    for (int m = 0; m < 2; ++m)
#pragma unroll
        for (int j = 0; j < 4; ++j) {
            const int r = wm * 32 + m * 16 + crow0 + j;
            const float sum = psum[r][0][0] + psum[r][1][0];
            const float sq  = psum[r][0][1] + psum[r][1][1];
            const float mean = sum * 0.0078125f;
            const float var = sq * 0.0078125f - mean * mean;
            mean_[m][j] = mean;
            rstd_[m][j] = rsqrtf(var + 1e-5f);
        }
#pragma unroll
    for (int m = 0; m < 2; ++m) {
        const int growb = r0 + wm * 32 + m * 16 + crow0;
#pragma unroll
        for (int n = 0; n < 4; ++n) {
            const int gcol = wn * 64 + n * 16 + ccol;
            const float sv = lns[gcol], bv2 = lnbi[gcol];
#pragma unroll
            for (int j = 0; j < 4; ++j) {
                const float y = (acc[m][n][j] - mean_[m][j]) * rstd_[m][j] * sv + bv2;
                const size_t oi = (size_t)(growb + j) * 128 + gcol;
                if (Co) Co[oi] = y;
                if (Cb) Cb[oi] = f2bf(y);
            }
        }
    }
}

// ---------------------------------------------------------------------------
// MFMA flash attention, encoder self-attn (verified r3).
// ---------------------------------------------------------------------------
__global__ __launch_bounds__(256) void k_attn_mfma(
    const ushort* __restrict__ qkv, ushort* __restrict__ ob, float scale)
{
    __shared__ ushort Ks[208 * 40];
    __shared__ ushort Vt[32 * 232];
    __shared__ ushort Ps[4][16 * 232];
    const int bh = blockIdx.x;
    const int b = bh >> 2, h = bh & 3;
    const int t = threadIdx.x, w = t >> 6, l = t & 63;
    const int lr = l & 15, lg = l >> 4;

    for (int idx = t; idx < 784; idx += 256) {
        const int j = idx >> 2, ch = idx & 3;
        const size_t base = ((size_t)j * 256 + b) * 384 + h * 32 + ch * 8;
        *(short8*)(Ks + j * 40 + ch * 8) = *(const short8*)(qkv + base + 128);
        short8 v = *(const short8*)(qkv + base + 256);
#pragma unroll
        for (int q = 0; q < 8; ++q)
            Vt[(ch * 8 + q) * 232 + j] = (ushort)v[q];
    }
    for (int idx = t; idx < 32 * 36; idx += 256)
        Vt[(idx / 36) * 232 + 196 + (idx % 36)] = 0;
    for (int i = l; i < 256; i += 64)
        Ps[w][(i >> 4) * 232 + 208 + (i & 15)] = 0;
    __syncthreads();

    for (int qt = w; qt < 13; qt += 4) {
        int qr = qt * 16 + lr; if (qr > 195) qr = 195;
        const bf16x8 qf = *(const bf16x8*)(qkv + ((size_t)qr * 256 + b) * 384 + h * 32 + lg * 8);

        f32x4 s[13];
#pragma unroll
        for (int jn = 0; jn < 13; ++jn) {
            const bf16x8 kf = *(const bf16x8*)(Ks + (jn * 16 + lr) * 40 + lg * 8);
            s[jn] = __builtin_amdgcn_mfma_f32_16x16x32_bf16(qf, kf, (f32x4)0.f, 0, 0, 0);
        }
        if (lr >= 4) {
            s[12][0] = -3.0e38f; s[12][1] = -3.0e38f;
            s[12][2] = -3.0e38f; s[12][3] = -3.0e38f;
        }

        float inv[4];
        ushort* pw = Ps[w];
#pragma unroll
        for (int j = 0; j < 4; ++j) {
            float m = s[0][j];
#pragma unroll
            for (int jn = 1; jn < 13; ++jn) m = fmaxf(m, s[jn][j]);
            m = fmaxf(m, __shfl_xor(m, 1, 64));
            m = fmaxf(m, __shfl_xor(m, 2, 64));
            m = fmaxf(m, __shfl_xor(m, 4, 64));
            m = fmaxf(m, __shfl_xor(m, 8, 64));
            float sum = 0.f;
#pragma unroll
            for (int jn = 0; jn < 13; ++jn) {
                const float p = __expf((s[jn][j] - m) * scale);
                s[jn][j] = p;
                sum += p;
            }
            sum += __shfl_xor(sum, 1, 64);
            sum += __shfl_xor(sum, 2, 64);
            sum += __shfl_xor(sum, 4, 64);
            sum += __shfl_xor(sum, 8, 64);
            inv[j] = 1.0f / sum;
        }
#pragma unroll
        for (int jn = 0; jn < 13; ++jn)
#pragma unroll
            for (int j = 0; j < 4; ++j)
                pw[(lg * 4 + j) * 232 + jn * 16 + lr] = f2bf(s[jn][j]);

        f32x4 o0 = (f32x4)0.f, o1 = (f32x4)0.f;
#pragma unroll
        for (int kt = 0; kt < 7; ++kt) {
            const bf16x8 pf = *(const bf16x8*)(pw + lr * 232 + kt * 32 + lg * 8);
            const bf16x8 v0 = *(const bf16x8*)(Vt + lr * 232 + kt * 32 + lg * 8);
            const bf16x8 v1 = *(const bf16x8*)(Vt + (16 + lr) * 232 + kt * 32 + lg * 8);
            o0 = __builtin_amdgcn_mfma_f32_16x16x32_bf16(pf, v0, o0, 0, 0, 0);
            o1 = __builtin_amdgcn_mfma_f32_16x16x32_bf16(pf, v1, o1, 0, 0, 0);
        }
#pragma unroll
        for (int j = 0; j < 4; ++j) {
            const int r = qt * 16 + lg * 4 + j;
            if (r < 196) {
                const size_t o = ((size_t)r * 256 + b) * 128 + h * 32;
                ob[o + lr]      = f2bf(o0[j] * inv[j]);
                ob[o + 16 + lr] = f2bf(o1[j] * inv[j]);
            }
        }
    }
}

// ---------------------------------------------------------------------------
// Fused attention (f32, decoder cross path; verified r1).
// ---------------------------------------------------------------------------
__global__ __launch_bounds__(256) void k_attn(
    const float* __restrict__ qp, int qstride,
    const float* __restrict__ kvp, int kvstride, int koff, int voff,
    float* __restrict__ op, ushort* __restrict__ ob,
    int Lq, int Lk, float scale)
{
    __shared__ float Kl[196 * 36];
    __shared__ float Vl[196 * 32];
    __shared__ float pbuf[4][256];
    const int bh = blockIdx.x;
    const int b = bh >> 2;
    const int h = bh & 3;
    const int t = threadIdx.x;
    const int w = t >> 6;
    const int l = t & 63;

    for (int idx = t; idx < Lk * 8; idx += 256) {
        const int j = idx >> 3;
        const int kq = idx & 7;
        const size_t row = ((size_t)j * 256 + b) * kvstride + h * 32 + kq * 4;
        *(float4*)(&Kl[j * 36 + kq * 4]) = *(const float4*)(kvp + row + koff);
        *(float4*)(&Vl[j * 32 + kq * 4]) = *(const float4*)(kvp + row + voff);
    }
    if ((Lk & 1) && t < 8) *(float4*)(&Vl[Lk * 32 + t * 4]) = make_float4(0.f, 0.f, 0.f, 0.f);
    __syncthreads();

    const int Lh = (Lk + 1) >> 1;
    const int half = l >> 5;
    const int kk = l & 31;
    const int jb = half * Lh;

    for (int jq = w; jq < Lq; jq += 4) {
        const float* qrow = qp + ((size_t)jq * 256 + b) * qstride + h * 32;
        float4 q4[8];
#pragma unroll
        for (int kq = 0; kq < 8; ++kq) q4[kq] = *(const float4*)(qrow + kq * 4);

        float s[4];
#pragma unroll
        for (int r = 0; r < 4; ++r) {
            const int j = l + (r << 6);
            float acc = -3.0e38f;
            if (j < Lk) {
                acc = 0.f;
#pragma unroll
                for (int kq = 0; kq < 8; ++kq) {
                    const float4 kv = *(const float4*)(&Kl[j * 36 + kq * 4]);
                    acc += q4[kq].x * kv.x + q4[kq].y * kv.y +
                           q4[kq].z * kv.z + q4[kq].w * kv.w;
                }
                acc *= scale;
            }
            s[r] = acc;
        }
        float m = fmaxf(fmaxf(s[0], s[1]), fmaxf(s[2], s[3]));
        m = wred_max(m);
        float sum = 0.f;
#pragma unroll
        for (int r = 0; r < 4; ++r) {
            const int j = l + (r << 6);
            float p = __expf(s[r] - m);
            if (j >= Lk) p = 0.f;
            pbuf[w][j] = p;
            sum += p;
        }
        sum = wred_sum(sum);
        const float inv = 1.0f / sum;
        __threadfence_block();

        float o = 0.f;
        for (int jj = 0; jj < Lh; ++jj) {
            const float pv = pbuf[w][jb + jj];
            const float vv = Vl[(jb + jj) * 32 + kk];
            o += pv * vv;
        }
        o += __shfl_xor(o, 32, 64);
        o *= inv;
        if (l < 32) {
            const size_t oi = ((size_t)jq * 256 + b) * 128 + h * 32 + l;
            if (op) op[oi] = o;
            if (ob) ob[oi] = f2bf(o);
        }
        __threadfence_block();
    }
}

// ---------------------------------------------------------------------------
// Fused decoder part 1 v3 (verified r9): K-split partial sums +
// load-once-FMA-many to break serial load->FMA chains.
// ---------------------------------------------------------------------------
__global__ __launch_bounds__(512) void k_dec1(
    const float* __restrict__ sk,
    const float* __restrict__ W1, const float* __restrict__ b1,
    const float* __restrict__ W2, const float* __restrict__ b2,
    const float* __restrict__ W3, const float* __restrict__ b3,
    const float* __restrict__ ang, const float* __restrict__ px,
    const float* __restrict__ py,
    const float* __restrict__ actW, const float* __restrict__ actb,
    const float* __restrict__ saW, const float* __restrict__ sab,
    const float* __restrict__ saoW, const float* __restrict__ saob,
    const float* __restrict__ ln1s, const float* __restrict__ ln1b,
    const float* __restrict__ caW, const float* __restrict__ cab,
    float* __restrict__ TGo, float* __restrict__ DQ)
{
    __shared__ float tg[15][128];
    __shared__ float qkv[15][388];   // +4 pad
    __shared__ float ao[15][128];
    __shared__ float xr[256], h1[256], h2[256];
    __shared__ float s3[100];
    __shared__ float hp[4][256];     // K-split partial sums (reused per phase)
    __shared__ float pbv[4][16];
    const int b = blockIdx.x, t = threadIdx.x;
    const int w = t >> 6, l = t & 63;

    if (t < 256) xr[t] = (t < 200) ? sk[(size_t)b * 200 + t] : 0.f;
    __syncthreads();
    {
        const int c = t & 255, g = t >> 8;
        const int k0 = g * 100;
        float a = 0.f;
#pragma unroll 10
        for (int k = k0; k < k0 + 100; ++k) a += xr[k] * W1[k * 256 + c];
        hp[g][c] = a;
    }
    __syncthreads();
    if (t < 256) h1[t] = fmaxf(hp[0][t] + hp[1][t] + b1[t], 0.f);
    __syncthreads();
    {
        const int c = t & 255, g = t >> 8;
        const int k0 = g * 128;
        float a = 0.f;
#pragma unroll 8
        for (int k = k0; k < k0 + 128; ++k) a += h1[k] * W2[k * 256 + c];
        hp[g][c] = a;
    }
    __syncthreads();
    if (t < 256) h2[t] = fmaxf(hp[0][t] + hp[1][t] + b2[t], 0.f);
    __syncthreads();
    if (t < 400) {
        const int c = t % 100, g = t / 100;
        const int k0 = g * 64;
        float a = 0.f;
#pragma unroll 8
        for (int k = k0; k < k0 + 64; ++k) a += h2[k] * W3[k * 100 + c];
        hp[g][c] = a;
    }
    __syncthreads();
    if (t < 100) s3[t] = hp[0][t] + hp[1][t] + hp[2][t] + hp[3][t] + b3[t];
    __syncthreads();
    {
        const int c = t & 127, g = t >> 7;
        const int k0 = g * 25;
        float a = 0.f;
#pragma unroll 5
        for (int k = k0; k < k0 + 25; ++k) a += s3[k] * actW[(18 + k) * 128 + c];
        hp[g][c] = a;
    }
    __syncthreads();
    if (t < 128) {
        const float base = actb[t] + hp[0][t] + hp[1][t] + hp[2][t] + hp[3][t] +
                           ang[b] * actW[15 * 128 + t] + px[b] * actW[16 * 128 + t] +
                           py[b] * actW[17 * 128 + t];
#pragma unroll
        for (int i = 0; i < 15; ++i) tg[i][t] = base + actW[i * 128 + t];
    }
    __syncthreads();

    if (t < 384) {
        float acc[15];
#pragma unroll
        for (int r = 0; r < 15; ++r) acc[r] = 0.f;
#pragma unroll 4
        for (int k = 0; k < 128; ++k) {
            const float wv = saW[(size_t)k * 384 + t];
#pragma unroll
            for (int r = 0; r < 15; ++r) acc[r] += tg[r][k] * wv;
        }
        const float bb = sab[t];
#pragma unroll
        for (int r = 0; r < 15; ++r) qkv[r][t] = acc[r] + bb;
    }
    __syncthreads();

    const float rs = 0.17677669529663687f;
    if (w < 4) {
        for (int qi = 0; qi < 15; ++qi) {
            float s = -3.0e38f;
            if (l < 15) {
                s = 0.f;
#pragma unroll
                for (int d = 0; d < 32; ++d)
                    s += qkv[qi][w * 32 + d] * qkv[l][128 + w * 32 + d];
                s *= rs;
            }
            const float m = wred_max(s);
            const float pv = (l < 15) ? __expf(s - m) : 0.f;
            const float sum = wred_sum(pv);
            if (l < 15) pbv[w][l] = pv;
            if (l < 32) {
                float o = 0.f;
#pragma unroll
                for (int j = 0; j < 15; ++j) o += pbv[w][j] * qkv[j][256 + w * 32 + l];
                ao[qi][w * 32 + l] = o / sum;
            }
        }
    }
    __syncthreads();

    {
        const int c = t & 127, g = t >> 7;
        const int r3 = (g + 12 < 15) ? g + 12 : 0;
        float a0 = 0.f, a1 = 0.f, a2 = 0.f, a3 = 0.f;
#pragma unroll 4
        for (int k = 0; k < 128; ++k) {
            const float wv = saoW[(size_t)k * 128 + c];
            a0 += ao[g][k] * wv;
            a1 += ao[g + 4][k] * wv;
            a2 += ao[g + 8][k] * wv;
            a3 += ao[r3][k] * wv;
        }
        const float bb = saob[c];
        qkv[g][c]     = a0 + bb + tg[g][c];
        qkv[g + 4][c] = a1 + bb + tg[g + 4][c];
        qkv[g + 8][c] = a2 + bb + tg[g + 8][c];
        if (g + 12 < 15) qkv[g + 12][c] = a3 + bb + tg[g + 12][c];
    }
    __syncthreads();
    for (int r = w; r < 15; r += 8) {
        const float x0 = qkv[r][l], x1 = qkv[r][l + 64];
        const float sm = wred_sum(x0 + x1);
        const float sq = wred_sum(x0 * x0 + x1 * x1);
        const float mean = sm * 0.0078125f;
        const float rstd = rsqrtf(sq * 0.0078125f - mean * mean + 1e-5f);
        const float y0 = (x0 - mean) * rstd * ln1s[l] + ln1b[l];
        const float y1 = (x1 - mean) * rstd * ln1s[l + 64] + ln1b[l + 64];
        tg[r][l] = y0; tg[r][l + 64] = y1;
        float* g2 = TGo + ((size_t)r * 256 + b) * 128;
        g2[l] = y0; g2[l + 64] = y1;
    }
    __syncthreads();

    {
        const int c = t & 127, g = t >> 7;
        const int r3 = (g + 12 < 15) ? g + 12 : 0;
        float a0 = 0.f, a1 = 0.f, a2 = 0.f, a3 = 0.f;
#pragma unroll 4
        for (int k = 0; k < 128; ++k) {
            const float wv = caW[(size_t)k * 384 + c];
            a0 += tg[g][k] * wv;
            a1 += tg[g + 4][k] * wv;
            a2 += tg[g + 8][k] * wv;
            a3 += tg[r3][k] * wv;
        }
        const float bb = cab[c];
        DQ[((size_t)g * 256 + b) * 128 + c]       = a0 + bb;
        DQ[((size_t)(g + 4) * 256 + b) * 128 + c] = a1 + bb;
        DQ[((size_t)(g + 8) * 256 + b) * 128 + c] = a2 + bb;
        if (g + 12 < 15) DQ[((size_t)(g + 12) * 256 + b) * 128 + c] = a3 + bb;
    }
}

// ---------------------------------------------------------------------------
// Fused decoder part 2 v3 (verified r9).
// ---------------------------------------------------------------------------
__global__ __launch_bounds__(512) void k_dec2(
    const float* __restrict__ TGo, const float* __restrict__ AT,
    const float* __restrict__ caoW, const float* __restrict__ caob,
    const float* __restrict__ ln2s, const float* __restrict__ ln2b,
    const float* __restrict__ ff1W, const float* __restrict__ ff1b,
    const float* __restrict__ ff2W, const float* __restrict__ ff2b,
    const float* __restrict__ ln3s, const float* __restrict__ ln3b,
    const float* __restrict__ ns, const float* __restrict__ nb,
    const float* __restrict__ l1W, const float* __restrict__ l1b,
    const float* __restrict__ l2w, const float* __restrict__ l2b,
    float* __restrict__ qout)
{
    __shared__ float tg[15][128], ao[15][128], o2[15][128];
    __shared__ float ff[15][64];
    const int b = blockIdx.x, t = threadIdx.x;
    const int w = t >> 6, l = t & 63;

    for (int idx = t; idx < 1920; idx += 512) {
        const int r = idx >> 7, c = idx & 127;
        tg[r][c] = TGo[((size_t)r * 256 + b) * 128 + c];
        ao[r][c] = AT[((size_t)r * 256 + b) * 128 + c];
    }
    __syncthreads();

    {
        const int c = t & 127, g = t >> 7;
        const int r3 = (g + 12 < 15) ? g + 12 : 0;
        float a0 = 0.f, a1 = 0.f, a2 = 0.f, a3 = 0.f;
#pragma unroll 4
        for (int k = 0; k < 128; ++k) {
            const float wv = caoW[(size_t)k * 128 + c];
            a0 += ao[g][k] * wv;
            a1 += ao[g + 4][k] * wv;
            a2 += ao[g + 8][k] * wv;
            a3 += ao[r3][k] * wv;
        }
        const float bb = caob[c];
        o2[g][c]     = a0 + bb + tg[g][c];
        o2[g + 4][c] = a1 + bb + tg[g + 4][c];
        o2[g + 8][c] = a2 + bb + tg[g + 8][c];
        if (g + 12 < 15) o2[g + 12][c] = a3 + bb + tg[g + 12][c];
    }
    __syncthreads();
    for (int r = w; r < 15; r += 8) {
        const float x0 = o2[r][l], x1 = o2[r][l + 64];
        const float sm = wred_sum(x0 + x1);
        const float sq = wred_sum(x0 * x0 + x1 * x1);
        const float mean = sm * 0.0078125f;
        const float rstd = rsqrtf(sq * 0.0078125f - mean * mean + 1e-5f);
        tg[r][l]      = (x0 - mean) * rstd * ln2s[l] + ln2b[l];
        tg[r][l + 64] = (x1 - mean) * rstd * ln2s[l + 64] + ln2b[l + 64];
    }
    __syncthreads();
    {
        const int n = t & 63, g = t >> 6;
        const int r1 = (g + 8 < 15) ? g + 8 : 0;
        float a0 = 0.f, a1 = 0.f;
#pragma unroll 4
        for (int k = 0; k < 128; ++k) {
            const float wv = ff1W[(size_t)k * 64 + n];
            a0 += tg[g][k] * wv;
            a1 += tg[r1][k] * wv;
        }
        const float bb = ff1b[n];
        ff[g][n] = fmaxf(a0 + bb, 0.f);
        if (g + 8 < 15) ff[g + 8][n] = fmaxf(a1 + bb, 0.f);
    }
    __syncthreads();
    {
        const int c = t & 127, g = t >> 7;
        const int r3 = (g + 12 < 15) ? g + 12 : 0;
        float a0 = 0.f, a1 = 0.f, a2 = 0.f, a3 = 0.f;
#pragma unroll 4
        for (int k = 0; k < 64; ++k) {
            const float wv = ff2W[(size_t)k * 128 + c];
            a0 += ff[g][k] * wv;
            a1 += ff[g + 4][k] * wv;
            a2 += ff[g + 8][k] * wv;
            a3 += ff[r3][k] * wv;
        }
        const float bb = ff2b[c];
        o2[g][c]     = a0 + bb + tg[g][c];
        o2[g + 4][c] = a1 + bb + tg[g + 4][c];
        o2[g + 8][c] = a2 + bb + tg[g + 8][c];
        if (g + 12 < 15) o2[g + 12][c] = a3 + bb + tg[g + 12][c];
    }
    __syncthreads();
    for (int r = w; r < 15; r += 8) {
        const float x0 = o2[r][l], x1 = o2[r][l + 64];
        const float sm = wred_sum(x0 + x1);
        const float sq = wred_sum(x0 * x0 + x1 * x1);
        const float mean = sm * 0.0078125f;
        const float rstd = rsqrtf(sq * 0.0078125f - mean * mean + 1e-5f);
        const float y0 = (x0 - mean) * rstd * ln3s[l] + ln3b[l];
        const float y1 = (x1 - mean) * rstd * ln3s[l + 64] + ln3b[l + 64];
        const float sm2 = wred_sum(y0 + y1);
        const float sq2 = wred_sum(y0 * y0 + y1 * y1);
        const float mean2 = sm2 * 0.0078125f;
        const float rstd2 = rsqrtf(sq2 * 0.0078125f - mean2 * mean2 + 1e-5f);
        tg[r][l]      = (y0 - mean2) * rstd2 * ns[l] + nb[l];
        tg[r][l + 64] = (y1 - mean2) * rstd2 * ns[l + 64] + nb[l + 64];
    }
    __syncthreads();
    {
        const int c = t & 127, g = t >> 7;
        const int r3 = (g + 12 < 15) ? g + 12 : 0;
        float a0 = 0.f, a1 = 0.f, a2 = 0.f, a3 = 0.f;
#pragma unroll 4
        for (int k = 0; k < 128; ++k) {
            const float wv = l1W[(size_t)k * 128 + c];
            a0 += tg[g][k] * wv;
            a1 += tg[g + 4][k] * wv;
            a2 += tg[g + 8][k] * wv;
            a3 += tg[r3][k] * wv;
        }
        const float bb = l1b[c];
        o2[g][c]     = fmaxf(a0 + bb, 0.f);
        o2[g + 4][c] = fmaxf(a1 + bb, 0.f);
        o2[g + 8][c] = fmaxf(a2 + bb, 0.f);
        if (g + 12 < 15) o2[g + 12][c] = fmaxf(a3 + bb, 0.f);
    }
    __syncthreads();
    for (int r = w; r < 15; r += 8) {
        const float d = wred_sum(o2[r][l] * l2w[l] + o2[r][l + 64] * l2w[l + 64]);
        if (l == 0) qout[b * 15 + r] = d + l2b[0];
    }
}

// ---------------------------------------------------------------------------
extern "C" void kernel_launch(void* const* d_in, const int* in_sizes, int n_in,
                              void* d_out, int out_size, void* d_ws, size_t ws_size,
                              hipStream_t stream)
{
    (void)in_sizes; (void)n_in; (void)out_size; (void)ws_size;
    const float* image      = (const float*)d_in[0];
    const float* angle      = (const float*)d_in[1];
    const float* pos_x      = (const float*)d_in[2];
    const float* pos_y      = (const float*)d_in[3];
    const float* sk         = (const float*)d_in[4];
    const float* patch_W    = (const float*)d_in[5];
    const float* patch_b    = (const float*)d_in[6];
    const float* pos_emb    = (const float*)d_in[7];
    const float* enc_qkv_W  = (const float*)d_in[8];
    const float* enc_qkv_b  = (const float*)d_in[9];
    const float* enc_out_W  = (const float*)d_in[10];
    const float* enc_out_b  = (const float*)d_in[11];
    const float* enc_ln1_s  = (const float*)d_in[12];
    const float* enc_ln1_b  = (const float*)d_in[13];
    const float* enc_ff1_W  = (const float*)d_in[14];
    const float* enc_ff1_b  = (const float*)d_in[15];
    const float* enc_ff2_W  = (const float*)d_in[16];
    const float* enc_ff2_b  = (const float*)d_in[17];
    const float* enc_ln2_s  = (const float*)d_in[18];
    const float* enc_ln2_b  = (const float*)d_in[19];
    const float* dec_sa_qkv_W = (const float*)d_in[20];
    const float* dec_sa_qkv_b = (const float*)d_in[21];
    const float* dec_sa_out_W = (const float*)d_in[22];
    const float* dec_sa_out_b = (const float*)d_in[23];
    const float* dec_ca_qkv_W = (const float*)d_in[24];
    const float* dec_ca_qkv_b = (const float*)d_in[25];
    const float* dec_ca_out_W = (const float*)d_in[26];
    const float* dec_ca_out_b = (const float*)d_in[27];
    const float* dec_ln1_s  = (const float*)d_in[28];
    const float* dec_ln1_b  = (const float*)d_in[29];
    const float* dec_ln2_s  = (const float*)d_in[30];
    const float* dec_ln2_b  = (const float*)d_in[31];
    const float* dec_ln3_s  = (const float*)d_in[32];
    const float* dec_ln3_b  = (const float*)d_in[33];
    const float* dec_ff1_W  = (const float*)d_in[34];
    const float* dec_ff1_b  = (const float*)d_in[35];
    const float* dec_ff2_W  = (const float*)d_in[36];
    const float* dec_ff2_b  = (const float*)d_in[37];
    const float* dec_norm_s = (const float*)d_in[38];
    const float* dec_norm_b = (const float*)d_in[39];
    const float* sk1_W = (const float*)d_in[40];
    const float* sk1_b = (const float*)d_in[41];
    const float* sk2_W = (const float*)d_in[42];
    const float* sk2_b = (const float*)d_in[43];
    const float* sk3_W = (const float*)d_in[44];
    const float* sk3_b = (const float*)d_in[45];
    const float* act_W = (const float*)d_in[46];
    const float* act_b = (const float*)d_in[47];
    const float* l1_W  = (const float*)d_in[48];
    const float* l1_b  = (const float*)d_in[49];
    const float* l2_W  = (const float*)d_in[50];
    const float* l2_b  = (const float*)d_in[51];

    // Workspace (float offsets)
    float* ws = (float*)d_ws;
    float* S0   = ws;               // src f32 residual stream  [6,422,528]
    float* QKVr = ws + 6422528;     // big overlay region       [19,267,584]
    float* T0   = ws + 25690112;    // decoder cross-attn out   [6,422,528]
    float* T1   = ws + 32112640;    // M0b bf16 home            [6,422,528]
    float* F1   = ws + 38535168;    // F1b bf16                 [3,211,264]
    float* M0r  = ws + 41746432;    // srcb/T0b | lnb bf16      [6,422,528]
    float* S1s  = ws + 48168960;
    float* TG   = S1s + 156672;     // tgt f32 15*256*128
    ushort* WTS = (ushort*)(ws + 48817152);

    // Overlays
    ushort* QKVb = (ushort*)QKVr;            // enc QKV bf16 [50176][384]
    float*  KV   = QKVr;                     // cross K/V f32 [50176][256]
    float* DQ   = QKVr + 14319616;           // dec cross Q f32
    float* DT0  = T0;
    ushort* srcb = (ushort*)M0r;
    ushort* T0b  = (ushort*)M0r;             // disjoint lifetime with srcb
    ushort* lnb  = (ushort*)(M0r + 3211264);
    ushort* F1b  = (ushort*)F1;
    ushort* M0b  = (ushort*)T1;
    ushort* wt_patch = WTS;
    ushort* wt_qkv   = WTS + 98304;
    ushort* wt_out   = WTS + 147456;
    ushort* wt_ff1   = WTS + 163840;
    ushort* wt_ff2   = WTS + 172032;
    ushort* wt_ckv   = WTS + 180224;

    const float rs = 0.17677669529663687f;  // 1/sqrt(32)

    // ---- prep ----
    k_wconv<<<dim3(832), 256, 0, stream>>>(patch_W, enc_qkv_W, enc_out_W,
                                           enc_ff1_W, enc_ff2_W, dec_ca_qkv_W, WTS);
    k_dec1<<<dim3(256), 512, 0, stream>>>(
        sk, sk1_W, sk1_b, sk2_W, sk2_b, sk3_W, sk3_b,
        angle, pos_x, pos_y, act_W, act_b,
        dec_sa_qkv_W, dec_sa_qkv_b, dec_sa_out_W, dec_sa_out_b,
        dec_ln1_s, dec_ln1_b, dec_ca_qkv_W, dec_ca_qkv_b, TG, DQ);

    // ---- encoder ----
    k_pgemm<<<dim3(784), 256, 0, stream>>>(
        image, wt_patch, patch_b, pos_emb, S0, srcb);
    k_gemm_bf16<64, 128><<<dim3(784, 3), 256, 0, stream>>>(
        srcb, 128, wt_qkv, 128, enc_qkv_b, nullptr, QKVb, 384, nullptr, 0);
    k_attn_mfma<<<dim3(1024), 256, 0, stream>>>(QKVb, T0b, rs);
    k_gemm_ln<<<dim3(784), 256, 0, stream>>>(                 // out-proj + LN1
        T0b, 128, wt_out, 128, enc_out_b, S0, enc_ln1_s, enc_ln1_b, S0, lnb);
    k_gemm_bf16<64, 64><<<dim3(784, 1), 256, 0, stream>>>(    // FF1 + relu
        lnb, 128, wt_ff1, 128, enc_ff1_b, nullptr, F1b, 64, nullptr, 1);
    k_gemm_ln<<<dim3(784), 256, 0, stream>>>(                 // FF2 + LN2
        F1b, 64, wt_ff2, 64, enc_ff2_b, S0, enc_ln2_s, enc_ln2_b, nullptr, M0b);
    k_gemm_bf16<64, 128><<<dim3(784, 2), 256, 0, stream>>>(   // cross K/V
        M0b, 128, wt_ckv, 128, dec_ca_qkv_b + 128, KV, nullptr, 256, nullptr, 0);

    // ---- decoder cross-attn + tail ----
    k_attn<<<dim3(1024), 256, 0, stream>>>(DQ, 128, KV, 256, 0, 128,
                                           DT0, nullptr, 15, 196, rs);
    k_dec2<<<dim3(256), 512, 0, stream>>>(
        TG, DT0, dec_ca_out_W, dec_ca_out_b, dec_ln2_s, dec_ln2_b,
        dec_ff1_W, dec_ff1_b, dec_ff2_W, dec_ff2_b,
        dec_ln3_s, dec_ln3_b, dec_norm_s, dec_norm_b,
        l1_W, l1_b, l2_W, l2_b, (float*)d_out);
}